// Round 14
// baseline (278.359 us; speedup 1.0000x reference)
//
#include <hip/hip_runtime.h>
#include <hip/hip_bf16.h>

#define B_    32
#define S_    256
#define BS_   8192      // B_*S_
#define Wc_   16        // chars per word
#define CDIM_ 16
#define CH_   16
#define WDIM_ 300
#define KX_   332       // WDIM_+2*CH_
#define XC_   336       // padded X row (84 float4)
#define GEN_  100
#define WVP_  104       // padded word_vecs row
#define WH_   32
#define NG_   128       // 4*WH_

constexpr size_t OFF_WV   = 0;                                   // [8192][104] f32 (unused after fusion)
constexpr size_t OFF_PRE  = OFF_WV   + (size_t)BS_*WVP_;         // [2][256][32][128]
constexpr size_t OFF_LO   = OFF_PRE  + (size_t)2*S_*B_*NG_;      // [8192][64]
constexpr size_t OFF_CHB  = OFF_LO   + (size_t)BS_*64;           // [8192][32] char h
constexpr size_t OFF_GWT  = OFF_CHB  + (size_t)BS_*32;           // [332][128]
constexpr size_t OFF_WIHT = OFF_GWT  + (size_t)KX_*128;          // [2][100][128]
constexpr size_t OFF_WHHT = OFF_WIHT + (size_t)2*GEN_*NG_;       // [2][32][128]
constexpr size_t OFF_OW   = OFF_WHHT + (size_t)2*WH_*NG_;        // [2][64]

// native-exp2 activations: v_exp_f32 + v_rcp_f32, ~3 insts vs ~11 for __ocml_expf
__device__ __forceinline__ float sigm(float x){
  return __builtin_amdgcn_rcpf(1.f + __builtin_amdgcn_exp2f(-1.44269504089f*x));
}
__device__ __forceinline__ float tanh_(float x){
  return 1.f - 2.f*__builtin_amdgcn_rcpf(1.f + __builtin_amdgcn_exp2f(2.88539008178f*x));
}
__device__ __forceinline__ float rdlane(float v, int lane){
  return __uint_as_float(__builtin_amdgcn_readlane(__float_as_uint(v), lane));
}

// ---------------- prep: transpose small weights ----------------
__global__ void k_prep(const float* gen_W, const float* wih_f, const float* wih_b,
                       const float* whh_f, const float* whh_b, const float* out_W,
                       float* ws){
  int idx = blockIdx.x*blockDim.x + threadIdx.x;
  int stride = gridDim.x*blockDim.x;
  for (int i = idx; i < GEN_*KX_; i += stride){       // gen_W [100][332] -> [k][j] stride 128
    int j = i / KX_, k = i - j*KX_;
    ws[OFF_GWT + (size_t)k*128 + j] = gen_W[i];
  }
  for (int i = idx; i < NG_*GEN_; i += stride){       // w_Wih [128][100] -> [k][g]
    int g = i / GEN_, k = i - g*GEN_;
    ws[OFF_WIHT + 0*GEN_*NG_ + (size_t)k*NG_ + g] = wih_f[i];
    ws[OFF_WIHT + 1*GEN_*NG_ + (size_t)k*NG_ + g] = wih_b[i];
  }
  for (int i = idx; i < NG_*WH_; i += stride){        // w_Whh [128][32] -> [k][g]
    int g = i / WH_, k = i - g*WH_;
    ws[OFF_WHHT + 0*WH_*NG_ + (size_t)k*NG_ + g] = whh_f[i];
    ws[OFF_WHHT + 1*WH_*NG_ + (size_t)k*NG_ + g] = whh_b[i];
  }
  for (int i = idx; i < 2*64; i += stride) ws[OFF_OW + i] = out_W[i];
}

// ---------------- char BiLSTM: lane = (seq, unit); 16 lanes/seq ----------------
__global__ void __launch_bounds__(256, 2) k_char(const int* char_ids, const float* char_table,
                       const float* Wih_f, const float* Whh_f, const float* b_f,
                       const float* Wih_b, const float* Whh_b, const float* b_b,
                       float* ws){
  __shared__ float xr[16*324];        // [s][t][k] row stride 20, s stride 324
  const int dir = blockIdx.x & 1;
  const int sg  = blockIdx.x >> 1;
  const int tid = threadIdx.x;
  const float* WI = dir ? Wih_b : Wih_f;
  const float* WH = dir ? Whh_b : Whh_f;
  const float* BB = dir ? b_b  : b_f;
  const int ls = tid >> 4, u = tid & 15;
  const int seq0 = sg * 16;
  {
    const int id = char_ids[(seq0 + ls)*Wc_ + u];
    const float4* sr = (const float4*)(char_table + (size_t)id*CDIM_);
    float4 v0 = sr[0], v1 = sr[1], v2 = sr[2], v3 = sr[3];
    float* xw = &xr[ls*324 + u*20];
    *(float4*)(xw+0)  = v0; *(float4*)(xw+4)  = v1;
    *(float4*)(xw+8)  = v2; *(float4*)(xw+12) = v3;
  }
  float wi[4][16];
  #pragma unroll
  for (int g = 0; g < 4; ++g){
    const float4* wr = (const float4*)(WI + (size_t)(g*16+u)*CDIM_);
    float4 a = wr[0], b = wr[1], c = wr[2], d = wr[3];
    wi[g][0]=a.x; wi[g][1]=a.y; wi[g][2]=a.z; wi[g][3]=a.w;
    wi[g][4]=b.x; wi[g][5]=b.y; wi[g][6]=b.z; wi[g][7]=b.w;
    wi[g][8]=c.x; wi[g][9]=c.y; wi[g][10]=c.z; wi[g][11]=c.w;
    wi[g][12]=d.x; wi[g][13]=d.y; wi[g][14]=d.z; wi[g][15]=d.w;
  }
  float bias[4];
  #pragma unroll
  for (int g = 0; g < 4; ++g) bias[g] = BB[g*16+u];
  __syncthreads();
  float xp[16][4];
  const float* xb = &xr[ls*324];
  #pragma unroll
  for (int p = 0; p < 16; ++p){
    const int tm = dir ? (15-p) : p;
    const float4 x0 = *(const float4*)(xb + tm*20 + 0);
    const float4 x1 = *(const float4*)(xb + tm*20 + 4);
    const float4 x2 = *(const float4*)(xb + tm*20 + 8);
    const float4 x3 = *(const float4*)(xb + tm*20 + 12);
    float xk[16] = {x0.x,x0.y,x0.z,x0.w, x1.x,x1.y,x1.z,x1.w,
                    x2.x,x2.y,x2.z,x2.w, x3.x,x3.y,x3.z,x3.w};
    #pragma unroll
    for (int g = 0; g < 4; ++g){
      float a0 = bias[g], a1 = 0.f;
      #pragma unroll
      for (int k = 0; k < 16; k += 2){ a0 += wi[g][k]*xk[k]; a1 += wi[g][k+1]*xk[k+1]; }
      xp[p][g] = a0 + a1;
    }
  }
  float wh[4][16];
  #pragma unroll
  for (int g = 0; g < 4; ++g){
    const float4* wr = (const float4*)(WH + (size_t)(g*16+u)*CH_);
    float4 a = wr[0], b = wr[1], c = wr[2], d = wr[3];
    wh[g][0]=a.x; wh[g][1]=a.y; wh[g][2]=a.z; wh[g][3]=a.w;
    wh[g][4]=b.x; wh[g][5]=b.y; wh[g][6]=b.z; wh[g][7]=b.w;
    wh[g][8]=c.x; wh[g][9]=c.y; wh[g][10]=c.z; wh[g][11]=c.w;
    wh[g][12]=d.x; wh[g][13]=d.y; wh[g][14]=d.z; wh[g][15]=d.w;
  }
  const int lbase = (tid & 63) & 48;
  float h = 0.f, c = 0.f;
  #pragma unroll
  for (int p = 0; p < 16; ++p){
    float ai = xp[p][0], af = xp[p][1], ag = xp[p][2], ao = xp[p][3];
    #pragma unroll
    for (int k = 0; k < 16; ++k){
      const float hk = __shfl(h, lbase + k, 64);
      ai += wh[0][k]*hk; af += wh[1][k]*hk;
      ag += wh[2][k]*hk; ao += wh[3][k]*hk;
    }
    c = sigm(af)*c + sigm(ai)*tanh_(ag);
    h = sigm(ao)*tanh_(c);
  }
  ws[OFF_CHB + (size_t)(seq0 + ls)*32 + dir*16 + u] = h;
}

// ---------------- fused gen + word-LSTM input projection ----------------
// phase1: X @ gen_W^T + b, gelu -> word_vecs kept in LDS
// phase2: word_vecs @ w_Wih^T + b -> pre[d][s][b][g]   (replaces k_wpre)
__global__ void k_genp(const int* word_ids, const float* word_table, const float* gen_b,
                       const float* wb_f, const float* wb_b, float* ws){
  __shared__ __align__(16) float xt[16*XC_];    // 21.5 KB
  __shared__ __align__(16) float wvs[16*WVP_];  // 6.5 KB
  __shared__ int wids[16];
  const int r0 = blockIdx.x*16;
  if (threadIdx.x < 16) wids[threadIdx.x] = word_ids[r0 + threadIdx.x];
  __syncthreads();
  float4* xt4 = (float4*)xt;
  for (int i = threadIdx.x; i < 16*75; i += 128){          // word part: 75 float4/row
    const int r = i/75, q = i - r*75;
    xt4[r*84 + q] = ((const float4*)(word_table + (size_t)wids[r]*WDIM_))[q];
  }
  for (int i = threadIdx.x; i < 16*8; i += 128){           // char part: 8 float4/row
    const int r = i >> 3, q = i & 7;
    xt4[r*84 + 75 + q] = ((const float4*)(ws + OFF_CHB + (size_t)(r0+r)*32))[q];
  }
  __syncthreads();
  const int j = threadIdx.x;                   // j<100 valid
  const float bj = (j < GEN_) ? gen_b[j] : 0.f;
  float acc[16];
  #pragma unroll
  for (int r = 0; r < 16; ++r) acc[r] = bj;
  const float* WT = ws + OFF_GWT;
  for (int k4 = 0; k4 < KX_/4; ++k4){
    const int k = k4*4;
    const float w0 = WT[(size_t)(k+0)*128 + j];
    const float w1 = WT[(size_t)(k+1)*128 + j];
    const float w2 = WT[(size_t)(k+2)*128 + j];
    const float w3 = WT[(size_t)(k+3)*128 + j];
    #pragma unroll
    for (int r = 0; r < 16; ++r){
      const float4 xv = xt4[r*84 + k4];
      acc[r] += w0*xv.x + w1*xv.y + w2*xv.z + w3*xv.w;
    }
  }
  if (j < GEN_){
    #pragma unroll
    for (int r = 0; r < 16; ++r){
      const float a = acc[r];
      wvs[r*WVP_ + j] = 0.5f*a*(1.f + erff(a*0.70710678118f));
    }
  }
  __syncthreads();
  // phase 2: pre-activation projection for both directions
  const int g = threadIdx.x;                   // all 128 valid
  #pragma unroll
  for (int d = 0; d < 2; ++d){
    const float* W2 = ws + OFF_WIHT + (size_t)d*GEN_*NG_;
    const float wb = (d ? wb_b : wb_f)[g];
    float ac2[16];
    #pragma unroll
    for (int r = 0; r < 16; ++r) ac2[r] = wb;
    for (int k4 = 0; k4 < GEN_/4; ++k4){
      const int k = k4*4;
      const float w0 = W2[(size_t)(k+0)*NG_ + g];
      const float w1 = W2[(size_t)(k+1)*NG_ + g];
      const float w2 = W2[(size_t)(k+2)*NG_ + g];
      const float w3 = W2[(size_t)(k+3)*NG_ + g];
      #pragma unroll
      for (int r = 0; r < 16; ++r){
        const float4 xv = *(const float4*)&wvs[r*WVP_ + k];
        ac2[r] += w0*xv.x + w1*xv.y + w2*xv.z + w3*xv.w;
      }
    }
    float* pre = ws + OFF_PRE + (size_t)d*S_*B_*NG_;
    #pragma unroll
    for (int r = 0; r < 16; ++r){
      const int row = r0 + r, bb = row >> 8, ss = row & 255;
      pre[((size_t)ss*B_ + bb)*NG_ + g] = ac2[r];
    }
  }
}

// ---------------- word BiLSTM scan: 2 chains (fwd+bwd of one n) per wave ----------------
// r14: r13 showed weights-resident (VGPR 88) changed nothing -> per-step is
// issue+dependency bound on a lone wave (~61% busy, ~40% stall). Two
// independent chains in one wave fill each other's stall slots; exp2-native
// activations cut ~45 inst/step/chain and ~60 cy off the serial chain.
// 32 blocks; 22.5KB LDS keeps the high register budget (r12 mechanism).
#define BN_ ((size_t)B_*NG_)
__global__ void __launch_bounds__(64) k_wlstm(const float* __restrict__ WHT,
                                              const float* __restrict__ PRE,
                                              float* __restrict__ LO){
  __shared__ __align__(16) float hring[5632];   // [2][32][36] used; size = occupancy lever
  const int n = blockIdx.x;             // 0..31
  const int l = threadIdx.x;
  float wAf[32], wBf[32], wAb[32], wBb[32];
  #pragma unroll
  for (int k = 0; k < 32; ++k){
    wAf[k] = WHT[(size_t)k*NG_ + l];
    wBf[k] = WHT[(size_t)k*NG_ + 64 + l];
    wAb[k] = WHT[(size_t)(32 + k)*NG_ + l];
    wBb[k] = WHT[(size_t)(32 + k)*NG_ + 64 + l];
  }
  const float* pf = PRE + (size_t)n*NG_;                   // fwd: step s at s*BN_
  const float* pb = PRE + (size_t)S_*BN_ + (size_t)n*NG_;  // bwd: step s at (S_-1-s)*BN_
  float cf = 0.f, hf = 0.f, cb = 0.f, hb = 0.f;

  // prefetch steps 0,1 of both chains (depth 2)
  float f0A = pf[l],          f0B = pf[64+l];
  float f1A = pf[BN_+l],      f1B = pf[BN_+64+l];
  float b0A = pb[(size_t)(S_-1)*BN_ + l], b0B = pb[(size_t)(S_-1)*BN_ + 64+l];
  float b1A = pb[(size_t)(S_-2)*BN_ + l], b1B = pb[(size_t)(S_-2)*BN_ + 64+l];

#define WSTEP2(FA, FB, BA, BB, sidx) { \
    float aAf0 = (FA), aAf1 = 0.f, aBf0 = (FB), aBf1 = 0.f; \
    float aAb0 = (BA), aAb1 = 0.f, aBb0 = (BB), aBb1 = 0.f; \
    _Pragma("unroll") \
    for (int k = 0; k < 32; k += 2){ \
      const float hf0 = rdlane(hf, k);   const float hf1 = rdlane(hf, k+1); \
      const float hb0 = rdlane(hb, k);   const float hb1 = rdlane(hb, k+1); \
      aAf0 += wAf[k]*hf0;   aBf0 += wBf[k]*hf0; \
      aAf1 += wAf[k+1]*hf1; aBf1 += wBf[k+1]*hf1; \
      aAb0 += wAb[k]*hb0;   aBb0 += wBb[k]*hb0; \
      aAb1 += wAb[k+1]*hb1; aBb1 += wBb[k+1]*hb1; \
    } \
    const float aAf = aAf0 + aAf1, aBf = aBf0 + aBf1; \
    const float aAb = aAb0 + aAb1, aBb = aBb0 + aBb1; \
    const float fgf = __shfl_xor(aAf, 32), ogf = __shfl_xor(aBf, 32); \
    const float fgb = __shfl_xor(aAb, 32), ogb = __shfl_xor(aBb, 32); \
    cf = sigm(fgf)*cf + sigm(aAf)*tanh_(aBf); \
    hf = sigm(ogf)*tanh_(cf); \
    cb = sigm(fgb)*cb + sigm(aAb)*tanh_(aBb); \
    hb = sigm(ogb)*tanh_(cb); \
    if (l < 32){ \
      hring[((sidx) & 31)*36 + l]        = hf; \
      hring[1152 + ((sidx) & 31)*36 + l] = hb; \
    } \
  }

  for (int s = 0; s < S_; s += 2){
    float nf0A=0.f,nf0B=0.f,nf1A=0.f,nf1B=0.f,nb0A=0.f,nb0B=0.f,nb1A=0.f,nb1B=0.f;
    if (s + 2 < S_){                     // prefetch steps s+2, s+3 of both chains
      nf0A = pf[(size_t)(s+2)*BN_ + l];   nf0B = pf[(size_t)(s+2)*BN_ + 64+l];
      nf1A = pf[(size_t)(s+3)*BN_ + l];   nf1B = pf[(size_t)(s+3)*BN_ + 64+l];
      nb0A = pb[(size_t)(S_-3-s)*BN_ + l]; nb0B = pb[(size_t)(S_-3-s)*BN_ + 64+l];
      nb1A = pb[(size_t)(S_-4-s)*BN_ + l]; nb1B = pb[(size_t)(S_-4-s)*BN_ + 64+l];
    }
    WSTEP2(f0A, f0B, b0A, b0B, s)
    WSTEP2(f1A, f1B, b1A, b1B, s+1)
    f0A=nf0A; f0B=nf0B; f1A=nf1A; f1B=nf1B;
    b0A=nb0A; b0B=nb0B; b1A=nb1A; b1B=nb1B;

    if ((s & 31) == 30){                 // flush 32 finished steps, both dirs
      const int s0 = s & ~31;
      const int srow = l >> 1, half = l & 1;
      {
        const int sf = s0 + srow;        // fwd time index
        const float4* src = (const float4*)&hring[srow*36 + half*16];
        float4* dst = (float4*)(LO + ((size_t)n*S_ + sf)*64 + half*16);
        dst[0]=src[0]; dst[1]=src[1]; dst[2]=src[2]; dst[3]=src[3];
      }
      {
        const int tb = S_ - 1 - (s0 + srow);   // bwd time index
        const float4* src = (const float4*)&hring[1152 + srow*36 + half*16];
        float4* dst = (float4*)(LO + ((size_t)n*S_ + tb)*64 + 32 + half*16);
        dst[0]=src[0]; dst[1]=src[1]; dst[2]=src[2]; dst[3]=src[3];
      }
    }
  }
#undef WSTEP2
}

// ---------------- output head: sigmoid(lstm_out @ out_W^T + b) -> f32 ----------------
__global__ void k_out(const float* ws, const float* out_b, float* out){
  const int row = blockIdx.x*blockDim.x + threadIdx.x;
  const float4* lo = (const float4*)(ws + OFF_LO + (size_t)row*64);
  const float* OW = ws + OFF_OW;
  float a0 = out_b[0], a1 = out_b[1];
  #pragma unroll
  for (int q = 0; q < 16; ++q){
    const float4 v = lo[q];
    a0 += OW[q*4+0]*v.x + OW[q*4+1]*v.y + OW[q*4+2]*v.z + OW[q*4+3]*v.w;
    a1 += OW[64+q*4+0]*v.x + OW[64+q*4+1]*v.y + OW[64+q*4+2]*v.z + OW[64+q*4+3]*v.w;
  }
  out[row*2+0] = sigm(a0);
  out[row*2+1] = sigm(a1);
}

extern "C" void kernel_launch(void* const* d_in, const int* in_sizes, int n_in,
                              void* d_out, int out_size, void* d_ws, size_t ws_size,
                              hipStream_t stream){
  (void)in_sizes; (void)n_in; (void)out_size; (void)ws_size;
  const int*   word_ids   = (const int*)  d_in[0];
  const int*   char_ids   = (const int*)  d_in[1];
  const float* word_table = (const float*)d_in[2];
  const float* char_table = (const float*)d_in[3];
  const float* c_Wih_f    = (const float*)d_in[4];
  const float* c_Whh_f    = (const float*)d_in[5];
  const float* c_b_f      = (const float*)d_in[6];
  const float* c_Wih_b    = (const float*)d_in[7];
  const float* c_Whh_b    = (const float*)d_in[8];
  const float* c_b_b      = (const float*)d_in[9];
  const float* gen_W      = (const float*)d_in[10];
  const float* gen_b      = (const float*)d_in[11];
  const float* w_Wih_f    = (const float*)d_in[12];
  const float* w_Whh_f    = (const float*)d_in[13];
  const float* w_b_f      = (const float*)d_in[14];
  const float* w_Wih_b    = (const float*)d_in[15];
  const float* w_Whh_b    = (const float*)d_in[16];
  const float* w_b_b      = (const float*)d_in[17];
  const float* out_W      = (const float*)d_in[18];
  const float* out_b      = (const float*)d_in[19];
  float* ws  = (float*)d_ws;
  float* out = (float*)d_out;

  hipLaunchKernelGGL(k_prep,  dim3(64),   dim3(256), 0, stream,
                     gen_W, w_Wih_f, w_Wih_b, w_Whh_f, w_Whh_b, out_W, ws);
  hipLaunchKernelGGL(k_char,  dim3(1024), dim3(256), 0, stream,
                     char_ids, char_table, c_Wih_f, c_Whh_f, c_b_f,
                     c_Wih_b, c_Whh_b, c_b_b, ws);
  hipLaunchKernelGGL(k_genp,  dim3(512),  dim3(128), 0, stream,
                     word_ids, word_table, gen_b, w_b_f, w_b_b, ws);
  hipLaunchKernelGGL(k_wlstm, dim3(32),   dim3(64),  0, stream,
                     ws + OFF_WHHT, ws + OFF_PRE, ws + OFF_LO);
  hipLaunchKernelGGL(k_out,   dim3(64),   dim3(128), 0, stream, ws, out_b, out);
}

// Round 15
// 273.684 us; speedup vs baseline: 1.0171x; 1.0171x over previous
//
#include <hip/hip_runtime.h>
#include <hip/hip_bf16.h>

#define B_    32
#define S_    256
#define BS_   8192      // B_*S_
#define Wc_   16        // chars per word
#define CDIM_ 16
#define CH_   16
#define WDIM_ 300
#define KX_   332       // WDIM_+2*CH_
#define XC_   336       // padded X row (84 float4)
#define GEN_  100
#define WVP_  104       // padded word_vecs row
#define WH_   32
#define NG_   128       // 4*WH_

constexpr size_t OFF_WV   = 0;                                   // [8192][104] f32 (unused after fusion)
constexpr size_t OFF_PRE  = OFF_WV   + (size_t)BS_*WVP_;         // [2][256][32][128]
constexpr size_t OFF_LO   = OFF_PRE  + (size_t)2*S_*B_*NG_;      // [8192][64]
constexpr size_t OFF_CHB  = OFF_LO   + (size_t)BS_*64;           // [8192][32] char h
constexpr size_t OFF_GWT  = OFF_CHB  + (size_t)BS_*32;           // [332][128]
constexpr size_t OFF_WIHT = OFF_GWT  + (size_t)KX_*128;          // [2][100][128]
constexpr size_t OFF_WHHT = OFF_WIHT + (size_t)2*GEN_*NG_;       // [2][32][128]
constexpr size_t OFF_OW   = OFF_WHHT + (size_t)2*WH_*NG_;        // [2][64]

// native-exp2 activations: v_exp_f32 + v_rcp_f32, ~3 insts vs ~11 for __ocml_expf
__device__ __forceinline__ float sigm(float x){
  return __builtin_amdgcn_rcpf(1.f + __builtin_amdgcn_exp2f(-1.44269504089f*x));
}
__device__ __forceinline__ float tanh_(float x){
  return 1.f - 2.f*__builtin_amdgcn_rcpf(1.f + __builtin_amdgcn_exp2f(2.88539008178f*x));
}
__device__ __forceinline__ float rdlane(float v, int lane){
  return __uint_as_float(__builtin_amdgcn_readlane(__float_as_uint(v), lane));
}

// ---------------- prep: transpose small weights ----------------
__global__ void k_prep(const float* gen_W, const float* wih_f, const float* wih_b,
                       const float* whh_f, const float* whh_b, const float* out_W,
                       float* ws){
  int idx = blockIdx.x*blockDim.x + threadIdx.x;
  int stride = gridDim.x*blockDim.x;
  for (int i = idx; i < GEN_*KX_; i += stride){       // gen_W [100][332] -> [k][j] stride 128
    int j = i / KX_, k = i - j*KX_;
    ws[OFF_GWT + (size_t)k*128 + j] = gen_W[i];
  }
  for (int i = idx; i < NG_*GEN_; i += stride){       // w_Wih [128][100] -> [k][g]
    int g = i / GEN_, k = i - g*GEN_;
    ws[OFF_WIHT + 0*GEN_*NG_ + (size_t)k*NG_ + g] = wih_f[i];
    ws[OFF_WIHT + 1*GEN_*NG_ + (size_t)k*NG_ + g] = wih_b[i];
  }
  for (int i = idx; i < NG_*WH_; i += stride){        // w_Whh [128][32] -> [k][g]
    int g = i / WH_, k = i - g*WH_;
    ws[OFF_WHHT + 0*WH_*NG_ + (size_t)k*NG_ + g] = whh_f[i];
    ws[OFF_WHHT + 1*WH_*NG_ + (size_t)k*NG_ + g] = whh_b[i];
  }
  for (int i = idx; i < 2*64; i += stride) ws[OFF_OW + i] = out_W[i];
}

// ---------------- char BiLSTM: lane = (seq, unit); 16 lanes/seq ----------------
__global__ void __launch_bounds__(256, 2) k_char(const int* char_ids, const float* char_table,
                       const float* Wih_f, const float* Whh_f, const float* b_f,
                       const float* Wih_b, const float* Whh_b, const float* b_b,
                       float* ws){
  __shared__ float xr[16*324];        // [s][t][k] row stride 20, s stride 324
  const int dir = blockIdx.x & 1;
  const int sg  = blockIdx.x >> 1;
  const int tid = threadIdx.x;
  const float* WI = dir ? Wih_b : Wih_f;
  const float* WH = dir ? Whh_b : Whh_f;
  const float* BB = dir ? b_b  : b_f;
  const int ls = tid >> 4, u = tid & 15;
  const int seq0 = sg * 16;
  {
    const int id = char_ids[(seq0 + ls)*Wc_ + u];
    const float4* sr = (const float4*)(char_table + (size_t)id*CDIM_);
    float4 v0 = sr[0], v1 = sr[1], v2 = sr[2], v3 = sr[3];
    float* xw = &xr[ls*324 + u*20];
    *(float4*)(xw+0)  = v0; *(float4*)(xw+4)  = v1;
    *(float4*)(xw+8)  = v2; *(float4*)(xw+12) = v3;
  }
  float wi[4][16];
  #pragma unroll
  for (int g = 0; g < 4; ++g){
    const float4* wr = (const float4*)(WI + (size_t)(g*16+u)*CDIM_);
    float4 a = wr[0], b = wr[1], c = wr[2], d = wr[3];
    wi[g][0]=a.x; wi[g][1]=a.y; wi[g][2]=a.z; wi[g][3]=a.w;
    wi[g][4]=b.x; wi[g][5]=b.y; wi[g][6]=b.z; wi[g][7]=b.w;
    wi[g][8]=c.x; wi[g][9]=c.y; wi[g][10]=c.z; wi[g][11]=c.w;
    wi[g][12]=d.x; wi[g][13]=d.y; wi[g][14]=d.z; wi[g][15]=d.w;
  }
  float bias[4];
  #pragma unroll
  for (int g = 0; g < 4; ++g) bias[g] = BB[g*16+u];
  __syncthreads();
  float xp[16][4];
  const float* xb = &xr[ls*324];
  #pragma unroll
  for (int p = 0; p < 16; ++p){
    const int tm = dir ? (15-p) : p;
    const float4 x0 = *(const float4*)(xb + tm*20 + 0);
    const float4 x1 = *(const float4*)(xb + tm*20 + 4);
    const float4 x2 = *(const float4*)(xb + tm*20 + 8);
    const float4 x3 = *(const float4*)(xb + tm*20 + 12);
    float xk[16] = {x0.x,x0.y,x0.z,x0.w, x1.x,x1.y,x1.z,x1.w,
                    x2.x,x2.y,x2.z,x2.w, x3.x,x3.y,x3.z,x3.w};
    #pragma unroll
    for (int g = 0; g < 4; ++g){
      float a0 = bias[g], a1 = 0.f;
      #pragma unroll
      for (int k = 0; k < 16; k += 2){ a0 += wi[g][k]*xk[k]; a1 += wi[g][k+1]*xk[k+1]; }
      xp[p][g] = a0 + a1;
    }
  }
  float wh[4][16];
  #pragma unroll
  for (int g = 0; g < 4; ++g){
    const float4* wr = (const float4*)(WH + (size_t)(g*16+u)*CH_);
    float4 a = wr[0], b = wr[1], c = wr[2], d = wr[3];
    wh[g][0]=a.x; wh[g][1]=a.y; wh[g][2]=a.z; wh[g][3]=a.w;
    wh[g][4]=b.x; wh[g][5]=b.y; wh[g][6]=b.z; wh[g][7]=b.w;
    wh[g][8]=c.x; wh[g][9]=c.y; wh[g][10]=c.z; wh[g][11]=c.w;
    wh[g][12]=d.x; wh[g][13]=d.y; wh[g][14]=d.z; wh[g][15]=d.w;
  }
  const int lbase = (tid & 63) & 48;
  float h = 0.f, c = 0.f;
  #pragma unroll
  for (int p = 0; p < 16; ++p){
    float ai = xp[p][0], af = xp[p][1], ag = xp[p][2], ao = xp[p][3];
    #pragma unroll
    for (int k = 0; k < 16; ++k){
      const float hk = __shfl(h, lbase + k, 64);
      ai += wh[0][k]*hk; af += wh[1][k]*hk;
      ag += wh[2][k]*hk; ao += wh[3][k]*hk;
    }
    c = sigm(af)*c + sigm(ai)*tanh_(ag);
    h = sigm(ao)*tanh_(c);
  }
  ws[OFF_CHB + (size_t)(seq0 + ls)*32 + dir*16 + u] = h;
}

// ---------------- fused gen + word-LSTM input projection ----------------
__global__ void k_genp(const int* word_ids, const float* word_table, const float* gen_b,
                       const float* wb_f, const float* wb_b, float* ws){
  __shared__ __align__(16) float xt[16*XC_];    // 21.5 KB
  __shared__ __align__(16) float wvs[16*WVP_];  // 6.5 KB
  __shared__ int wids[16];
  const int r0 = blockIdx.x*16;
  if (threadIdx.x < 16) wids[threadIdx.x] = word_ids[r0 + threadIdx.x];
  __syncthreads();
  float4* xt4 = (float4*)xt;
  for (int i = threadIdx.x; i < 16*75; i += 128){          // word part: 75 float4/row
    const int r = i/75, q = i - r*75;
    xt4[r*84 + q] = ((const float4*)(word_table + (size_t)wids[r]*WDIM_))[q];
  }
  for (int i = threadIdx.x; i < 16*8; i += 128){           // char part: 8 float4/row
    const int r = i >> 3, q = i & 7;
    xt4[r*84 + 75 + q] = ((const float4*)(ws + OFF_CHB + (size_t)(r0+r)*32))[q];
  }
  __syncthreads();
  const int j = threadIdx.x;                   // j<100 valid
  const float bj = (j < GEN_) ? gen_b[j] : 0.f;
  float acc[16];
  #pragma unroll
  for (int r = 0; r < 16; ++r) acc[r] = bj;
  const float* WT = ws + OFF_GWT;
  for (int k4 = 0; k4 < KX_/4; ++k4){
    const int k = k4*4;
    const float w0 = WT[(size_t)(k+0)*128 + j];
    const float w1 = WT[(size_t)(k+1)*128 + j];
    const float w2 = WT[(size_t)(k+2)*128 + j];
    const float w3 = WT[(size_t)(k+3)*128 + j];
    #pragma unroll
    for (int r = 0; r < 16; ++r){
      const float4 xv = xt4[r*84 + k4];
      acc[r] += w0*xv.x + w1*xv.y + w2*xv.z + w3*xv.w;
    }
  }
  if (j < GEN_){
    #pragma unroll
    for (int r = 0; r < 16; ++r){
      const float a = acc[r];
      wvs[r*WVP_ + j] = 0.5f*a*(1.f + erff(a*0.70710678118f));
    }
  }
  __syncthreads();
  // phase 2: pre-activation projection for both directions
  const int g = threadIdx.x;                   // all 128 valid
  #pragma unroll
  for (int d = 0; d < 2; ++d){
    const float* W2 = ws + OFF_WIHT + (size_t)d*GEN_*NG_;
    const float wb = (d ? wb_b : wb_f)[g];
    float ac2[16];
    #pragma unroll
    for (int r = 0; r < 16; ++r) ac2[r] = wb;
    for (int k4 = 0; k4 < GEN_/4; ++k4){
      const int k = k4*4;
      const float w0 = W2[(size_t)(k+0)*NG_ + g];
      const float w1 = W2[(size_t)(k+1)*NG_ + g];
      const float w2 = W2[(size_t)(k+2)*NG_ + g];
      const float w3 = W2[(size_t)(k+3)*NG_ + g];
      #pragma unroll
      for (int r = 0; r < 16; ++r){
        const float4 xv = *(const float4*)&wvs[r*WVP_ + k];
        ac2[r] += w0*xv.x + w1*xv.y + w2*xv.z + w3*xv.w;
      }
    }
    float* pre = ws + OFF_PRE + (size_t)d*S_*B_*NG_;
    #pragma unroll
    for (int r = 0; r < 16; ++r){
      const int row = r0 + r, bb = row >> 8, ss = row & 255;
      pre[((size_t)ss*B_ + bb)*NG_ + g] = ac2[r];
    }
  }
}

// ---------------- word BiLSTM scan: 2 SAME-DIRECTION chains per wave ----------------
// r15: r14 failed because 2 directions need 128 weight regs > the ~92 budget.
// Two chains of the SAME direction (batch rows n0,n1) SHARE wA/wB: 64 weight
// regs — exactly the footprint r13 proved resident (VGPR 88). Chain B's FMAs
// fill chain A's dependency stalls (~40% of cycles in r13). Grid 32 =
// 2 dirs x 16 row-pairs. 22.5KB LDS keeps the register budget (r12 lever).
#define BN_ ((size_t)B_*NG_)
__global__ void __launch_bounds__(64) k_wlstm(const float* __restrict__ WHT,
                                              const float* __restrict__ PRE,
                                              float* __restrict__ LO){
  __shared__ __align__(16) float hring[5632];   // [2 chains][32][36] used; size = occupancy lever
  const int d  = blockIdx.x >> 4;       // direction
  const int pr = blockIdx.x & 15;       // row pair
  const int n0 = pr*2, n1 = n0 + 1;
  const int l = threadIdx.x;
  const float* WT = WHT + (size_t)d*WH_*NG_;
  float wA[32], wB[32];                 // shared across both chains
  #pragma unroll
  for (int k = 0; k < 32; ++k){ wA[k] = WT[(size_t)k*NG_ + l]; wB[k] = WT[(size_t)k*NG_ + 64 + l]; }
  // p0 points at (time-start, n0); chain1 = +NG_; step stride = stp
  const float* p0 = PRE + (size_t)d*S_*BN_ + (size_t)n0*NG_ + (size_t)(d ? (S_-1) : 0)*BN_;
  const ptrdiff_t stp = (d ? -1 : 1) * (ptrdiff_t)BN_;
  float c0 = 0.f, h0 = 0.f, c1 = 0.f, h1 = 0.f;

  // prefetch steps 0,1 of both chains (depth 2)
  float s0A0 = p0[l],           s0B0 = p0[64+l];
  float s0A1 = p0[NG_+l],       s0B1 = p0[NG_+64+l];
  float s1A0 = p0[stp+l],       s1B0 = p0[stp+64+l];
  float s1A1 = p0[stp+NG_+l],   s1B1 = p0[stp+NG_+64+l];

#define WSTEP2(PA0, PB0, PA1, PB1, sidx) { \
    float aA00 = (PA0), aA01 = 0.f, aB00 = (PB0), aB01 = 0.f; \
    float aA10 = (PA1), aA11 = 0.f, aB10 = (PB1), aB11 = 0.f; \
    _Pragma("unroll") \
    for (int k = 0; k < 32; k += 2){ \
      const float ha0 = rdlane(h0, k);   const float ha1 = rdlane(h0, k+1); \
      const float hb0 = rdlane(h1, k);   const float hb1 = rdlane(h1, k+1); \
      aA00 += wA[k]*ha0;   aB00 += wB[k]*ha0; \
      aA01 += wA[k+1]*ha1; aB01 += wB[k+1]*ha1; \
      aA10 += wA[k]*hb0;   aB10 += wB[k]*hb0; \
      aA11 += wA[k+1]*hb1; aB11 += wB[k+1]*hb1; \
    } \
    const float aA0 = aA00 + aA01, aB0 = aB00 + aB01; \
    const float aA1 = aA10 + aA11, aB1 = aB10 + aB11; \
    const float fg0 = __shfl_xor(aA0, 32), og0 = __shfl_xor(aB0, 32); \
    const float fg1 = __shfl_xor(aA1, 32), og1 = __shfl_xor(aB1, 32); \
    c0 = sigm(fg0)*c0 + sigm(aA0)*tanh_(aB0); \
    h0 = sigm(og0)*tanh_(c0); \
    c1 = sigm(fg1)*c1 + sigm(aA1)*tanh_(aB1); \
    h1 = sigm(og1)*tanh_(c1); \
    if (l < 32){ \
      hring[((sidx) & 31)*36 + l]        = h0; \
      hring[1152 + ((sidx) & 31)*36 + l] = h1; \
    } \
  }

  for (int s = 0; s < S_; s += 2){
    float nA00=0.f,nB00=0.f,nA01=0.f,nB01=0.f,nA10=0.f,nB10=0.f,nA11=0.f,nB11=0.f;
    if (s + 2 < S_){                     // prefetch steps s+2, s+3 of both chains
      const float* q = p0 + (ptrdiff_t)(s+2)*stp;
      nA00 = q[l];            nB00 = q[64+l];
      nA01 = q[NG_+l];        nB01 = q[NG_+64+l];
      nA10 = q[stp+l];        nB10 = q[stp+64+l];
      nA11 = q[stp+NG_+l];    nB11 = q[stp+NG_+64+l];
    }
    WSTEP2(s0A0, s0B0, s0A1, s0B1, s)
    WSTEP2(s1A0, s1B0, s1A1, s1B1, s+1)
    s0A0=nA00; s0B0=nB00; s0A1=nA01; s0B1=nB01;
    s1A0=nA10; s1B0=nB10; s1A1=nA11; s1B1=nB11;

    if ((s & 31) == 30){                 // flush 32 finished steps, both chains
      const int s0i = s & ~31;
      const int srow = l >> 1, half = l & 1;
      const int ss = d ? (S_ - 1 - (s0i + srow)) : (s0i + srow);
      {
        const float4* src = (const float4*)&hring[srow*36 + half*16];
        float4* dst = (float4*)(LO + ((size_t)n0*S_ + ss)*64 + d*32 + half*16);
        dst[0]=src[0]; dst[1]=src[1]; dst[2]=src[2]; dst[3]=src[3];
      }
      {
        const float4* src = (const float4*)&hring[1152 + srow*36 + half*16];
        float4* dst = (float4*)(LO + ((size_t)n1*S_ + ss)*64 + d*32 + half*16);
        dst[0]=src[0]; dst[1]=src[1]; dst[2]=src[2]; dst[3]=src[3];
      }
    }
  }
#undef WSTEP2
}

// ---------------- output head: sigmoid(lstm_out @ out_W^T + b) -> f32 ----------------
__global__ void k_out(const float* ws, const float* out_b, float* out){
  const int row = blockIdx.x*blockDim.x + threadIdx.x;
  const float4* lo = (const float4*)(ws + OFF_LO + (size_t)row*64);
  const float* OW = ws + OFF_OW;
  float a0 = out_b[0], a1 = out_b[1];
  #pragma unroll
  for (int q = 0; q < 16; ++q){
    const float4 v = lo[q];
    a0 += OW[q*4+0]*v.x + OW[q*4+1]*v.y + OW[q*4+2]*v.z + OW[q*4+3]*v.w;
    a1 += OW[64+q*4+0]*v.x + OW[64+q*4+1]*v.y + OW[64+q*4+2]*v.z + OW[64+q*4+3]*v.w;
  }
  out[row*2+0] = sigm(a0);
  out[row*2+1] = sigm(a1);
}

extern "C" void kernel_launch(void* const* d_in, const int* in_sizes, int n_in,
                              void* d_out, int out_size, void* d_ws, size_t ws_size,
                              hipStream_t stream){
  (void)in_sizes; (void)n_in; (void)out_size; (void)ws_size;
  const int*   word_ids   = (const int*)  d_in[0];
  const int*   char_ids   = (const int*)  d_in[1];
  const float* word_table = (const float*)d_in[2];
  const float* char_table = (const float*)d_in[3];
  const float* c_Wih_f    = (const float*)d_in[4];
  const float* c_Whh_f    = (const float*)d_in[5];
  const float* c_b_f      = (const float*)d_in[6];
  const float* c_Wih_b    = (const float*)d_in[7];
  const float* c_Whh_b    = (const float*)d_in[8];
  const float* c_b_b      = (const float*)d_in[9];
  const float* gen_W      = (const float*)d_in[10];
  const float* gen_b      = (const float*)d_in[11];
  const float* w_Wih_f    = (const float*)d_in[12];
  const float* w_Whh_f    = (const float*)d_in[13];
  const float* w_b_f      = (const float*)d_in[14];
  const float* w_Wih_b    = (const float*)d_in[15];
  const float* w_Whh_b    = (const float*)d_in[16];
  const float* w_b_b      = (const float*)d_in[17];
  const float* out_W      = (const float*)d_in[18];
  const float* out_b      = (const float*)d_in[19];
  float* ws  = (float*)d_ws;
  float* out = (float*)d_out;

  hipLaunchKernelGGL(k_prep,  dim3(64),   dim3(256), 0, stream,
                     gen_W, w_Wih_f, w_Wih_b, w_Whh_f, w_Whh_b, out_W, ws);
  hipLaunchKernelGGL(k_char,  dim3(1024), dim3(256), 0, stream,
                     char_ids, char_table, c_Wih_f, c_Whh_f, c_b_f,
                     c_Wih_b, c_Whh_b, c_b_b, ws);
  hipLaunchKernelGGL(k_genp,  dim3(512),  dim3(128), 0, stream,
                     word_ids, word_table, gen_b, w_b_f, w_b_b, ws);
  hipLaunchKernelGGL(k_wlstm, dim3(32),   dim3(64),  0, stream,
                     ws + OFF_WHHT, ws + OFF_PRE, ws + OFF_LO);
  hipLaunchKernelGGL(k_out,   dim3(64),   dim3(128), 0, stream, ws, out_b, out);
}

// Round 16
// 187.495 us; speedup vs baseline: 1.4846x; 1.4597x over previous
//
#include <hip/hip_runtime.h>
#include <hip/hip_bf16.h>

#define B_    32
#define S_    256
#define BS_   8192      // B_*S_
#define Wc_   16        // chars per word
#define CDIM_ 16
#define CH_   16
#define WDIM_ 300
#define KX_   332       // WDIM_+2*CH_
#define XC_   336       // padded X row (84 float4)
#define GEN_  100
#define WVP_  104       // padded word_vecs row
#define WH_   32
#define NG_   128       // 4*WH_

constexpr size_t OFF_WV   = 0;                                   // [8192][104] f32 (unused after fusion)
constexpr size_t OFF_PRE  = OFF_WV   + (size_t)BS_*WVP_;         // [2][256][32][128]
constexpr size_t OFF_LO   = OFF_PRE  + (size_t)2*S_*B_*NG_;      // [8192][64]
constexpr size_t OFF_CHB  = OFF_LO   + (size_t)BS_*64;           // [8192][32] char h
constexpr size_t OFF_GWT  = OFF_CHB  + (size_t)BS_*32;           // [332][128]
constexpr size_t OFF_WIHT = OFF_GWT  + (size_t)KX_*128;          // [2][100][128]
constexpr size_t OFF_WHHT = OFF_WIHT + (size_t)2*GEN_*NG_;       // [2][32][128]
constexpr size_t OFF_OW   = OFF_WHHT + (size_t)2*WH_*NG_;        // [2][64]

typedef __attribute__((ext_vector_type(2))) float f2;

// native-exp2 activations: v_exp_f32 + v_rcp_f32, ~3 insts vs ~11 for __ocml_expf
__device__ __forceinline__ float sigm(float x){
  return __builtin_amdgcn_rcpf(1.f + __builtin_amdgcn_exp2f(-1.44269504089f*x));
}
__device__ __forceinline__ float tanh_(float x){
  return 1.f - 2.f*__builtin_amdgcn_rcpf(1.f + __builtin_amdgcn_exp2f(2.88539008178f*x));
}
__device__ __forceinline__ float rdlane(float v, int lane){
  return __uint_as_float(__builtin_amdgcn_readlane(__float_as_uint(v), lane));
}

// ---------------- prep: transpose small weights ----------------
__global__ void k_prep(const float* gen_W, const float* wih_f, const float* wih_b,
                       const float* whh_f, const float* whh_b, const float* out_W,
                       float* ws){
  int idx = blockIdx.x*blockDim.x + threadIdx.x;
  int stride = gridDim.x*blockDim.x;
  for (int i = idx; i < GEN_*KX_; i += stride){       // gen_W [100][332] -> [k][j] stride 128
    int j = i / KX_, k = i - j*KX_;
    ws[OFF_GWT + (size_t)k*128 + j] = gen_W[i];
  }
  for (int i = idx; i < NG_*GEN_; i += stride){       // w_Wih [128][100] -> [k][g]
    int g = i / GEN_, k = i - g*GEN_;
    ws[OFF_WIHT + 0*GEN_*NG_ + (size_t)k*NG_ + g] = wih_f[i];
    ws[OFF_WIHT + 1*GEN_*NG_ + (size_t)k*NG_ + g] = wih_b[i];
  }
  for (int i = idx; i < NG_*WH_; i += stride){        // w_Whh [128][32] -> [k][g]
    int g = i / WH_, k = i - g*WH_;
    ws[OFF_WHHT + 0*WH_*NG_ + (size_t)k*NG_ + g] = whh_f[i];
    ws[OFF_WHHT + 1*WH_*NG_ + (size_t)k*NG_ + g] = whh_b[i];
  }
  for (int i = idx; i < 2*64; i += stride) ws[OFF_OW + i] = out_W[i];
}

// ---------------- char BiLSTM: lane = (seq, unit); 16 lanes/seq ----------------
__global__ void __launch_bounds__(256, 2) k_char(const int* char_ids, const float* char_table,
                       const float* Wih_f, const float* Whh_f, const float* b_f,
                       const float* Wih_b, const float* Whh_b, const float* b_b,
                       float* ws){
  __shared__ float xr[16*324];        // [s][t][k] row stride 20, s stride 324
  const int dir = blockIdx.x & 1;
  const int sg  = blockIdx.x >> 1;
  const int tid = threadIdx.x;
  const float* WI = dir ? Wih_b : Wih_f;
  const float* WH = dir ? Whh_b : Whh_f;
  const float* BB = dir ? b_b  : b_f;
  const int ls = tid >> 4, u = tid & 15;
  const int seq0 = sg * 16;
  {
    const int id = char_ids[(seq0 + ls)*Wc_ + u];
    const float4* sr = (const float4*)(char_table + (size_t)id*CDIM_);
    float4 v0 = sr[0], v1 = sr[1], v2 = sr[2], v3 = sr[3];
    float* xw = &xr[ls*324 + u*20];
    *(float4*)(xw+0)  = v0; *(float4*)(xw+4)  = v1;
    *(float4*)(xw+8)  = v2; *(float4*)(xw+12) = v3;
  }
  float wi[4][16];
  #pragma unroll
  for (int g = 0; g < 4; ++g){
    const float4* wr = (const float4*)(WI + (size_t)(g*16+u)*CDIM_);
    float4 a = wr[0], b = wr[1], c = wr[2], d = wr[3];
    wi[g][0]=a.x; wi[g][1]=a.y; wi[g][2]=a.z; wi[g][3]=a.w;
    wi[g][4]=b.x; wi[g][5]=b.y; wi[g][6]=b.z; wi[g][7]=b.w;
    wi[g][8]=c.x; wi[g][9]=c.y; wi[g][10]=c.z; wi[g][11]=c.w;
    wi[g][12]=d.x; wi[g][13]=d.y; wi[g][14]=d.z; wi[g][15]=d.w;
  }
  float bias[4];
  #pragma unroll
  for (int g = 0; g < 4; ++g) bias[g] = BB[g*16+u];
  __syncthreads();
  float xp[16][4];
  const float* xb = &xr[ls*324];
  #pragma unroll
  for (int p = 0; p < 16; ++p){
    const int tm = dir ? (15-p) : p;
    const float4 x0 = *(const float4*)(xb + tm*20 + 0);
    const float4 x1 = *(const float4*)(xb + tm*20 + 4);
    const float4 x2 = *(const float4*)(xb + tm*20 + 8);
    const float4 x3 = *(const float4*)(xb + tm*20 + 12);
    float xk[16] = {x0.x,x0.y,x0.z,x0.w, x1.x,x1.y,x1.z,x1.w,
                    x2.x,x2.y,x2.z,x2.w, x3.x,x3.y,x3.z,x3.w};
    #pragma unroll
    for (int g = 0; g < 4; ++g){
      float a0 = bias[g], a1 = 0.f;
      #pragma unroll
      for (int k = 0; k < 16; k += 2){ a0 += wi[g][k]*xk[k]; a1 += wi[g][k+1]*xk[k+1]; }
      xp[p][g] = a0 + a1;
    }
  }
  float wh[4][16];
  #pragma unroll
  for (int g = 0; g < 4; ++g){
    const float4* wr = (const float4*)(WH + (size_t)(g*16+u)*CH_);
    float4 a = wr[0], b = wr[1], c = wr[2], d = wr[3];
    wh[g][0]=a.x; wh[g][1]=a.y; wh[g][2]=a.z; wh[g][3]=a.w;
    wh[g][4]=b.x; wh[g][5]=b.y; wh[g][6]=b.z; wh[g][7]=b.w;
    wh[g][8]=c.x; wh[g][9]=c.y; wh[g][10]=c.z; wh[g][11]=c.w;
    wh[g][12]=d.x; wh[g][13]=d.y; wh[g][14]=d.z; wh[g][15]=d.w;
  }
  const int lbase = (tid & 63) & 48;
  float h = 0.f, c = 0.f;
  #pragma unroll
  for (int p = 0; p < 16; ++p){
    float ai = xp[p][0], af = xp[p][1], ag = xp[p][2], ao = xp[p][3];
    #pragma unroll
    for (int k = 0; k < 16; ++k){
      const float hk = __shfl(h, lbase + k, 64);
      ai += wh[0][k]*hk; af += wh[1][k]*hk;
      ag += wh[2][k]*hk; ao += wh[3][k]*hk;
    }
    c = sigm(af)*c + sigm(ai)*tanh_(ag);
    h = sigm(ao)*tanh_(c);
  }
  ws[OFF_CHB + (size_t)(seq0 + ls)*32 + dir*16 + u] = h;
}

// ---------------- fused gen + word-LSTM input projection ----------------
__global__ void k_genp(const int* word_ids, const float* word_table, const float* gen_b,
                       const float* wb_f, const float* wb_b, float* ws){
  __shared__ __align__(16) float xt[16*XC_];    // 21.5 KB
  __shared__ __align__(16) float wvs[16*WVP_];  // 6.5 KB
  __shared__ int wids[16];
  const int r0 = blockIdx.x*16;
  if (threadIdx.x < 16) wids[threadIdx.x] = word_ids[r0 + threadIdx.x];
  __syncthreads();
  float4* xt4 = (float4*)xt;
  for (int i = threadIdx.x; i < 16*75; i += 128){          // word part: 75 float4/row
    const int r = i/75, q = i - r*75;
    xt4[r*84 + q] = ((const float4*)(word_table + (size_t)wids[r]*WDIM_))[q];
  }
  for (int i = threadIdx.x; i < 16*8; i += 128){           // char part: 8 float4/row
    const int r = i >> 3, q = i & 7;
    xt4[r*84 + 75 + q] = ((const float4*)(ws + OFF_CHB + (size_t)(r0+r)*32))[q];
  }
  __syncthreads();
  const int j = threadIdx.x;                   // j<100 valid
  const float bj = (j < GEN_) ? gen_b[j] : 0.f;
  float acc[16];
  #pragma unroll
  for (int r = 0; r < 16; ++r) acc[r] = bj;
  const float* WT = ws + OFF_GWT;
  for (int k4 = 0; k4 < KX_/4; ++k4){
    const int k = k4*4;
    const float w0 = WT[(size_t)(k+0)*128 + j];
    const float w1 = WT[(size_t)(k+1)*128 + j];
    const float w2 = WT[(size_t)(k+2)*128 + j];
    const float w3 = WT[(size_t)(k+3)*128 + j];
    #pragma unroll
    for (int r = 0; r < 16; ++r){
      const float4 xv = xt4[r*84 + k4];
      acc[r] += w0*xv.x + w1*xv.y + w2*xv.z + w3*xv.w;
    }
  }
  if (j < GEN_){
    #pragma unroll
    for (int r = 0; r < 16; ++r){
      const float a = acc[r];
      wvs[r*WVP_ + j] = 0.5f*a*(1.f + erff(a*0.70710678118f));
    }
  }
  __syncthreads();
  // phase 2: pre-activation projection for both directions
  const int g = threadIdx.x;                   // all 128 valid
  #pragma unroll
  for (int d = 0; d < 2; ++d){
    const float* W2 = ws + OFF_WIHT + (size_t)d*GEN_*NG_;
    const float wb = (d ? wb_b : wb_f)[g];
    float ac2[16];
    #pragma unroll
    for (int r = 0; r < 16; ++r) ac2[r] = wb;
    for (int k4 = 0; k4 < GEN_/4; ++k4){
      const int k = k4*4;
      const float w0 = W2[(size_t)(k+0)*NG_ + g];
      const float w1 = W2[(size_t)(k+1)*NG_ + g];
      const float w2 = W2[(size_t)(k+2)*NG_ + g];
      const float w3 = W2[(size_t)(k+3)*NG_ + g];
      #pragma unroll
      for (int r = 0; r < 16; ++r){
        const float4 xv = *(const float4*)&wvs[r*WVP_ + k];
        ac2[r] += w0*xv.x + w1*xv.y + w2*xv.z + w3*xv.w;
      }
    }
    float* pre = ws + OFF_PRE + (size_t)d*S_*B_*NG_;
    #pragma unroll
    for (int r = 0; r < 16; ++r){
      const int row = r0 + r, bb = row >> 8, ss = row & 255;
      pre[((size_t)ss*B_ + bb)*NG_ + g] = ac2[r];
    }
  }
}

// ---------------- word BiLSTM scan: 1 wave per (dir, batch row), packed FMAs ----------------
// r16: r15 proved the lone wave is ISSUE-RATE bound (~5-6 cy/inst; 2 chains ->
// 2x time, ILP gained nothing). So cut instructions: weights as float2 pairs
// (wA[k],wB[k]) and v_pk_fma_f32 accumulates (aA,aB) together — 64 FMA -> 32
// pk_fma, ~32 fewer VALU/step. Structure otherwise = r13 (92us, VGPR 88).
#define BN_ ((size_t)B_*NG_)
__global__ void __launch_bounds__(64) k_wlstm(const float* __restrict__ WHT,
                                              const float* __restrict__ PRE,
                                              float* __restrict__ LO){
  __shared__ __align__(16) float hring[5632];   // [32][36] used; size = VGPR-budget lever (r12)
  const int pair = blockIdx.x;          // 0..63
  const int d = pair >> 5;
  const int n = pair & 31;
  const int l = threadIdx.x;
  const float* WT = WHT + (size_t)d*WH_*NG_;
  f2 w2[32];                            // (wA[k], wB[k]) — gates l and 64+l
  #pragma unroll
  for (int k = 0; k < 32; ++k){
    w2[k] = (f2){ WT[(size_t)k*NG_ + l], WT[(size_t)k*NG_ + 64 + l] };
  }
  const float* pre = PRE + (size_t)d*S_*BN_ + (size_t)n*NG_;
  const float* p0 = pre + (size_t)(d ? (S_-1) : 0)*BN_;
  const ptrdiff_t stp = (d ? -1 : 1) * (ptrdiff_t)BN_;
  float cst = 0.f, h = 0.f;

  // prefetch steps 0..3
  float a0A = p0[0*stp + l], a0B = p0[0*stp + 64 + l];
  float a1A = p0[1*stp + l], a1B = p0[1*stp + 64 + l];
  float a2A = p0[2*stp + l], a2B = p0[2*stp + 64 + l];
  float a3A = p0[3*stp + l], a3B = p0[3*stp + 64 + l];

#define WSTEP(pAv, pBv, sidx) { \
    f2 q0 = (f2){(pAv),(pBv)}, q1 = (f2){0.f,0.f}, q2 = (f2){0.f,0.f}, q3 = (f2){0.f,0.f}; \
    _Pragma("unroll") \
    for (int k = 0; k < 32; k += 4){ \
      const float h0 = rdlane(h, k+0); \
      const float h1 = rdlane(h, k+1); \
      const float h2 = rdlane(h, k+2); \
      const float h3 = rdlane(h, k+3); \
      q0 += w2[k+0] * (f2){h0,h0}; \
      q1 += w2[k+1] * (f2){h1,h1}; \
      q2 += w2[k+2] * (f2){h2,h2}; \
      q3 += w2[k+3] * (f2){h3,h3}; \
    } \
    const f2 qs = (q0+q1)+(q2+q3); \
    const float aA = qs.x;                  /* lanes<32: i, lanes>=32: f */ \
    const float aB = qs.y;                  /* lanes<32: g, lanes>=32: o */ \
    const float fga = __shfl_xor(aA, 32);   /* lanes<32 receive f */ \
    const float oga = __shfl_xor(aB, 32);   /* lanes<32 receive o */ \
    const float cc = sigm(fga)*cst + sigm(aA)*tanh_(aB);  /* valid lanes<32 */ \
    cst = cc; \
    h = sigm(oga)*tanh_(cc);                               /* valid lanes<32 */ \
    if (l < 32) hring[((sidx) & 31)*36 + l] = h; \
  }

  for (int t = 0; t < S_; t += 4){
    float n0A=0.f, n0B=0.f, n1A=0.f, n1B=0.f, n2A=0.f, n2B=0.f, n3A=0.f, n3B=0.f;
    if (t + 4 < S_){                     // issue prefetch for steps t+4..t+7 FIRST
      const float* q = p0 + (ptrdiff_t)(t+4)*stp;
      n0A = q[0*stp + l]; n0B = q[0*stp + 64 + l];
      n1A = q[1*stp + l]; n1B = q[1*stp + 64 + l];
      n2A = q[2*stp + l]; n2B = q[2*stp + 64 + l];
      n3A = q[3*stp + l]; n3B = q[3*stp + 64 + l];
    }
    WSTEP(a0A, a0B, t+0)
    WSTEP(a1A, a1B, t+1)
    WSTEP(a2A, a2B, t+2)
    WSTEP(a3A, a3B, t+3)
    a0A=n0A; a0B=n0B; a1A=n1A; a1B=n1B;
    a2A=n2A; a2B=n2B; a3A=n3A; a3B=n3B;

    if ((t & 31) == 28){                 // flush steps s0..s0+31 coalesced
      const int s0 = t & ~31;
      const int srow = l >> 1, half = l & 1;
      const int s = s0 + srow;
      const int ss = d ? (S_ - 1 - s) : s;
      const float4* src = (const float4*)&hring[srow*36 + half*16];
      float4* dst = (float4*)(LO + ((size_t)n*S_ + ss)*64 + d*32 + half*16);
      dst[0] = src[0]; dst[1] = src[1]; dst[2] = src[2]; dst[3] = src[3];
    }
  }
#undef WSTEP
}

// ---------------- output head: sigmoid(lstm_out @ out_W^T + b) -> f32 ----------------
__global__ void k_out(const float* ws, const float* out_b, float* out){
  const int row = blockIdx.x*blockDim.x + threadIdx.x;
  const float4* lo = (const float4*)(ws + OFF_LO + (size_t)row*64);
  const float* OW = ws + OFF_OW;
  float a0 = out_b[0], a1 = out_b[1];
  #pragma unroll
  for (int q = 0; q < 16; ++q){
    const float4 v = lo[q];
    a0 += OW[q*4+0]*v.x + OW[q*4+1]*v.y + OW[q*4+2]*v.z + OW[q*4+3]*v.w;
    a1 += OW[64+q*4+0]*v.x + OW[64+q*4+1]*v.y + OW[64+q*4+2]*v.z + OW[64+q*4+3]*v.w;
  }
  out[row*2+0] = sigm(a0);
  out[row*2+1] = sigm(a1);
}

extern "C" void kernel_launch(void* const* d_in, const int* in_sizes, int n_in,
                              void* d_out, int out_size, void* d_ws, size_t ws_size,
                              hipStream_t stream){
  (void)in_sizes; (void)n_in; (void)out_size; (void)ws_size;
  const int*   word_ids   = (const int*)  d_in[0];
  const int*   char_ids   = (const int*)  d_in[1];
  const float* word_table = (const float*)d_in[2];
  const float* char_table = (const float*)d_in[3];
  const float* c_Wih_f    = (const float*)d_in[4];
  const float* c_Whh_f    = (const float*)d_in[5];
  const float* c_b_f      = (const float*)d_in[6];
  const float* c_Wih_b    = (const float*)d_in[7];
  const float* c_Whh_b    = (const float*)d_in[8];
  const float* c_b_b      = (const float*)d_in[9];
  const float* gen_W      = (const float*)d_in[10];
  const float* gen_b      = (const float*)d_in[11];
  const float* w_Wih_f    = (const float*)d_in[12];
  const float* w_Whh_f    = (const float*)d_in[13];
  const float* w_b_f      = (const float*)d_in[14];
  const float* w_Wih_b    = (const float*)d_in[15];
  const float* w_Whh_b    = (const float*)d_in[16];
  const float* w_b_b      = (const float*)d_in[17];
  const float* out_W      = (const float*)d_in[18];
  const float* out_b      = (const float*)d_in[19];
  float* ws  = (float*)d_ws;
  float* out = (float*)d_out;

  hipLaunchKernelGGL(k_prep,  dim3(64),   dim3(256), 0, stream,
                     gen_W, w_Wih_f, w_Wih_b, w_Whh_f, w_Whh_b, out_W, ws);
  hipLaunchKernelGGL(k_char,  dim3(1024), dim3(256), 0, stream,
                     char_ids, char_table, c_Wih_f, c_Whh_f, c_b_f,
                     c_Wih_b, c_Whh_b, c_b_b, ws);
  hipLaunchKernelGGL(k_genp,  dim3(512),  dim3(128), 0, stream,
                     word_ids, word_table, gen_b, w_b_f, w_b_b, ws);
  hipLaunchKernelGGL(k_wlstm, dim3(64),   dim3(64),  0, stream,
                     ws + OFF_WHHT, ws + OFF_PRE, ws + OFF_LO);
  hipLaunchKernelGGL(k_out,   dim3(64),   dim3(128), 0, stream, ws, out_b, out);
}

// Round 17
// 187.073 us; speedup vs baseline: 1.4880x; 1.0023x over previous
//
#include <hip/hip_runtime.h>
#include <hip/hip_bf16.h>

#define B_    32
#define S_    256
#define BS_   8192      // B_*S_
#define Wc_   16        // chars per word
#define CDIM_ 16
#define CH_   16
#define WDIM_ 300
#define KX_   332       // WDIM_+2*CH_
#define XC_   336       // padded X row (84 float4)
#define GEN_  100
#define WVP_  104       // padded word_vecs row
#define WH_   32
#define NG_   128       // 4*WH_

constexpr size_t OFF_WV   = 0;                                   // [8192][104] f32 (unused after fusion)
constexpr size_t OFF_PRE  = OFF_WV   + (size_t)BS_*WVP_;         // [2][256][32][128]
constexpr size_t OFF_LO   = OFF_PRE  + (size_t)2*S_*B_*NG_;      // [8192][64]
constexpr size_t OFF_CHB  = OFF_LO   + (size_t)BS_*64;           // [8192][32] char h
constexpr size_t OFF_GWT  = OFF_CHB  + (size_t)BS_*32;           // [332][128]
constexpr size_t OFF_WIHT = OFF_GWT  + (size_t)KX_*128;          // [2][100][128]
constexpr size_t OFF_WHHT = OFF_WIHT + (size_t)2*GEN_*NG_;       // [2][32][128]
constexpr size_t OFF_OW   = OFF_WHHT + (size_t)2*WH_*NG_;        // [2][64]

typedef __attribute__((ext_vector_type(2))) float f2;

// native-exp2 activations: v_exp_f32 + v_rcp_f32, ~3 insts vs ~11 for __ocml_expf
__device__ __forceinline__ float sigm(float x){
  return __builtin_amdgcn_rcpf(1.f + __builtin_amdgcn_exp2f(-1.44269504089f*x));
}
__device__ __forceinline__ float tanh_(float x){
  return 1.f - 2.f*__builtin_amdgcn_rcpf(1.f + __builtin_amdgcn_exp2f(2.88539008178f*x));
}
__device__ __forceinline__ float rdlane(float v, int lane){
  return __uint_as_float(__builtin_amdgcn_readlane(__float_as_uint(v), lane));
}

// ---------------- prep: transpose small weights ----------------
__global__ void k_prep(const float* gen_W, const float* wih_f, const float* wih_b,
                       const float* whh_f, const float* whh_b, const float* out_W,
                       float* ws){
  int idx = blockIdx.x*blockDim.x + threadIdx.x;
  int stride = gridDim.x*blockDim.x;
  for (int i = idx; i < GEN_*KX_; i += stride){       // gen_W [100][332] -> [k][j] stride 128
    int j = i / KX_, k = i - j*KX_;
    ws[OFF_GWT + (size_t)k*128 + j] = gen_W[i];
  }
  for (int i = idx; i < NG_*GEN_; i += stride){       // w_Wih [128][100] -> [k][g]
    int g = i / GEN_, k = i - g*GEN_;
    ws[OFF_WIHT + 0*GEN_*NG_ + (size_t)k*NG_ + g] = wih_f[i];
    ws[OFF_WIHT + 1*GEN_*NG_ + (size_t)k*NG_ + g] = wih_b[i];
  }
  for (int i = idx; i < NG_*WH_; i += stride){        // w_Whh [128][32] -> [k][g]
    int g = i / WH_, k = i - g*WH_;
    ws[OFF_WHHT + 0*WH_*NG_ + (size_t)k*NG_ + g] = whh_f[i];
    ws[OFF_WHHT + 1*WH_*NG_ + (size_t)k*NG_ + g] = whh_b[i];
  }
  for (int i = idx; i < 2*64; i += stride) ws[OFF_OW + i] = out_W[i];
}

// ---------------- char BiLSTM: lane = (seq, unit); 16 lanes/seq ----------------
// r17: +19KB LDS pad (guarded dead write). Mechanism (r12/r13): the VGPR
// budget is occupancy-heuristic-driven; at 20.7KB/256thr it targets ~7
// waves/SIMD -> ~73-reg budget, but this kernel has ~140 live floats in the
// xp phase -> scratch spills (the suspected bulk of the invisible ~105us
// remainder). 40KB -> 3 blocks/CU -> ~170-reg budget -> no spills, still
// 3 waves/SIMD of TLP.
__global__ void __launch_bounds__(256, 2) k_char(const int* char_ids, const float* char_table,
                       const float* Wih_f, const float* Whh_f, const float* b_f,
                       const float* Wih_b, const float* Whh_b, const float* b_b,
                       float* ws){
  __shared__ float xr[16*324];        // [s][t][k] row stride 20, s stride 324
  __shared__ float occ_pad[4864];     // 19KB: VGPR-budget lever, never written in practice
  const int dir = blockIdx.x & 1;
  const int sg  = blockIdx.x >> 1;
  const int tid = threadIdx.x;
  const float* WI = dir ? Wih_b : Wih_f;
  const float* WH = dir ? Whh_b : Whh_f;
  const float* BB = dir ? b_b  : b_f;
  const int ls = tid >> 4, u = tid & 15;
  const int seq0 = sg * 16;
  {
    const int id = char_ids[(seq0 + ls)*Wc_ + u];
    const float4* sr = (const float4*)(char_table + (size_t)id*CDIM_);
    float4 v0 = sr[0], v1 = sr[1], v2 = sr[2], v3 = sr[3];
    float* xw = &xr[ls*324 + u*20];
    *(float4*)(xw+0)  = v0; *(float4*)(xw+4)  = v1;
    *(float4*)(xw+8)  = v2; *(float4*)(xw+12) = v3;
    if (__builtin_expect(id == 0x7fffffff, 0)) occ_pad[tid] = v0.x;  // unprovable-dead
  }
  float wi[4][16];
  #pragma unroll
  for (int g = 0; g < 4; ++g){
    const float4* wr = (const float4*)(WI + (size_t)(g*16+u)*CDIM_);
    float4 a = wr[0], b = wr[1], c = wr[2], d = wr[3];
    wi[g][0]=a.x; wi[g][1]=a.y; wi[g][2]=a.z; wi[g][3]=a.w;
    wi[g][4]=b.x; wi[g][5]=b.y; wi[g][6]=b.z; wi[g][7]=b.w;
    wi[g][8]=c.x; wi[g][9]=c.y; wi[g][10]=c.z; wi[g][11]=c.w;
    wi[g][12]=d.x; wi[g][13]=d.y; wi[g][14]=d.z; wi[g][15]=d.w;
  }
  float bias[4];
  #pragma unroll
  for (int g = 0; g < 4; ++g) bias[g] = BB[g*16+u];
  __syncthreads();
  float xp[16][4];
  const float* xb = &xr[ls*324];
  #pragma unroll
  for (int p = 0; p < 16; ++p){
    const int tm = dir ? (15-p) : p;
    const float4 x0 = *(const float4*)(xb + tm*20 + 0);
    const float4 x1 = *(const float4*)(xb + tm*20 + 4);
    const float4 x2 = *(const float4*)(xb + tm*20 + 8);
    const float4 x3 = *(const float4*)(xb + tm*20 + 12);
    float xk[16] = {x0.x,x0.y,x0.z,x0.w, x1.x,x1.y,x1.z,x1.w,
                    x2.x,x2.y,x2.z,x2.w, x3.x,x3.y,x3.z,x3.w};
    #pragma unroll
    for (int g = 0; g < 4; ++g){
      float a0 = bias[g], a1 = 0.f;
      #pragma unroll
      for (int k = 0; k < 16; k += 2){ a0 += wi[g][k]*xk[k]; a1 += wi[g][k+1]*xk[k+1]; }
      xp[p][g] = a0 + a1;
    }
  }
  float wh[4][16];
  #pragma unroll
  for (int g = 0; g < 4; ++g){
    const float4* wr = (const float4*)(WH + (size_t)(g*16+u)*CH_);
    float4 a = wr[0], b = wr[1], c = wr[2], d = wr[3];
    wh[g][0]=a.x; wh[g][1]=a.y; wh[g][2]=a.z; wh[g][3]=a.w;
    wh[g][4]=b.x; wh[g][5]=b.y; wh[g][6]=b.z; wh[g][7]=b.w;
    wh[g][8]=c.x; wh[g][9]=c.y; wh[g][10]=c.z; wh[g][11]=c.w;
    wh[g][12]=d.x; wh[g][13]=d.y; wh[g][14]=d.z; wh[g][15]=d.w;
  }
  const int lbase = (tid & 63) & 48;
  float h = 0.f, c = 0.f;
  #pragma unroll
  for (int p = 0; p < 16; ++p){
    float ai = xp[p][0], af = xp[p][1], ag = xp[p][2], ao = xp[p][3];
    #pragma unroll
    for (int k = 0; k < 16; ++k){
      const float hk = __shfl(h, lbase + k, 64);
      ai += wh[0][k]*hk; af += wh[1][k]*hk;
      ag += wh[2][k]*hk; ao += wh[3][k]*hk;
    }
    c = sigm(af)*c + sigm(ai)*tanh_(ag);
    h = sigm(ao)*tanh_(c);
  }
  ws[OFF_CHB + (size_t)(seq0 + ls)*32 + dir*16 + u] = h;
}

// ---------------- fused gen + word-LSTM input projection ----------------
__global__ void k_genp(const int* word_ids, const float* word_table, const float* gen_b,
                       const float* wb_f, const float* wb_b, float* ws){
  __shared__ __align__(16) float xt[16*XC_];    // 21.5 KB
  __shared__ __align__(16) float wvs[16*WVP_];  // 6.5 KB
  __shared__ int wids[16];
  const int r0 = blockIdx.x*16;
  if (threadIdx.x < 16) wids[threadIdx.x] = word_ids[r0 + threadIdx.x];
  __syncthreads();
  float4* xt4 = (float4*)xt;
  for (int i = threadIdx.x; i < 16*75; i += 128){          // word part: 75 float4/row
    const int r = i/75, q = i - r*75;
    xt4[r*84 + q] = ((const float4*)(word_table + (size_t)wids[r]*WDIM_))[q];
  }
  for (int i = threadIdx.x; i < 16*8; i += 128){           // char part: 8 float4/row
    const int r = i >> 3, q = i & 7;
    xt4[r*84 + 75 + q] = ((const float4*)(ws + OFF_CHB + (size_t)(r0+r)*32))[q];
  }
  __syncthreads();
  const int j = threadIdx.x;                   // j<100 valid
  const float bj = (j < GEN_) ? gen_b[j] : 0.f;
  float acc[16];
  #pragma unroll
  for (int r = 0; r < 16; ++r) acc[r] = bj;
  const float* WT = ws + OFF_GWT;
  for (int k4 = 0; k4 < KX_/4; ++k4){
    const int k = k4*4;
    const float w0 = WT[(size_t)(k+0)*128 + j];
    const float w1 = WT[(size_t)(k+1)*128 + j];
    const float w2 = WT[(size_t)(k+2)*128 + j];
    const float w3 = WT[(size_t)(k+3)*128 + j];
    #pragma unroll
    for (int r = 0; r < 16; ++r){
      const float4 xv = xt4[r*84 + k4];
      acc[r] += w0*xv.x + w1*xv.y + w2*xv.z + w3*xv.w;
    }
  }
  if (j < GEN_){
    #pragma unroll
    for (int r = 0; r < 16; ++r){
      const float a = acc[r];
      wvs[r*WVP_ + j] = 0.5f*a*(1.f + erff(a*0.70710678118f));
    }
  }
  __syncthreads();
  // phase 2: pre-activation projection for both directions
  const int g = threadIdx.x;                   // all 128 valid
  #pragma unroll
  for (int d = 0; d < 2; ++d){
    const float* W2 = ws + OFF_WIHT + (size_t)d*GEN_*NG_;
    const float wb = (d ? wb_b : wb_f)[g];
    float ac2[16];
    #pragma unroll
    for (int r = 0; r < 16; ++r) ac2[r] = wb;
    for (int k4 = 0; k4 < GEN_/4; ++k4){
      const int k = k4*4;
      const float w0 = W2[(size_t)(k+0)*NG_ + g];
      const float w1 = W2[(size_t)(k+1)*NG_ + g];
      const float w2 = W2[(size_t)(k+2)*NG_ + g];
      const float w3 = W2[(size_t)(k+3)*NG_ + g];
      #pragma unroll
      for (int r = 0; r < 16; ++r){
        const float4 xv = *(const float4*)&wvs[r*WVP_ + k];
        ac2[r] += w0*xv.x + w1*xv.y + w2*xv.z + w3*xv.w;
      }
    }
    float* pre = ws + OFF_PRE + (size_t)d*S_*B_*NG_;
    #pragma unroll
    for (int r = 0; r < 16; ++r){
      const int row = r0 + r, bb = row >> 8, ss = row & 255;
      pre[((size_t)ss*B_ + bb)*NG_ + g] = ac2[r];
    }
  }
}

// ---------------- word BiLSTM scan: 1 wave per (dir, batch row), packed FMAs ----------------
// (r16 best: 82.5us, VGPR 88 — unchanged this round)
#define BN_ ((size_t)B_*NG_)
__global__ void __launch_bounds__(64) k_wlstm(const float* __restrict__ WHT,
                                              const float* __restrict__ PRE,
                                              float* __restrict__ LO){
  __shared__ __align__(16) float hring[5632];   // [32][36] used; size = VGPR-budget lever (r12)
  const int pair = blockIdx.x;          // 0..63
  const int d = pair >> 5;
  const int n = pair & 31;
  const int l = threadIdx.x;
  const float* WT = WHT + (size_t)d*WH_*NG_;
  f2 w2[32];                            // (wA[k], wB[k]) — gates l and 64+l
  #pragma unroll
  for (int k = 0; k < 32; ++k){
    w2[k] = (f2){ WT[(size_t)k*NG_ + l], WT[(size_t)k*NG_ + 64 + l] };
  }
  const float* pre = PRE + (size_t)d*S_*BN_ + (size_t)n*NG_;
  const float* p0 = pre + (size_t)(d ? (S_-1) : 0)*BN_;
  const ptrdiff_t stp = (d ? -1 : 1) * (ptrdiff_t)BN_;
  float cst = 0.f, h = 0.f;

  // prefetch steps 0..3
  float a0A = p0[0*stp + l], a0B = p0[0*stp + 64 + l];
  float a1A = p0[1*stp + l], a1B = p0[1*stp + 64 + l];
  float a2A = p0[2*stp + l], a2B = p0[2*stp + 64 + l];
  float a3A = p0[3*stp + l], a3B = p0[3*stp + 64 + l];

#define WSTEP(pAv, pBv, sidx) { \
    f2 q0 = (f2){(pAv),(pBv)}, q1 = (f2){0.f,0.f}, q2 = (f2){0.f,0.f}, q3 = (f2){0.f,0.f}; \
    _Pragma("unroll") \
    for (int k = 0; k < 32; k += 4){ \
      const float h0 = rdlane(h, k+0); \
      const float h1 = rdlane(h, k+1); \
      const float h2 = rdlane(h, k+2); \
      const float h3 = rdlane(h, k+3); \
      q0 += w2[k+0] * (f2){h0,h0}; \
      q1 += w2[k+1] * (f2){h1,h1}; \
      q2 += w2[k+2] * (f2){h2,h2}; \
      q3 += w2[k+3] * (f2){h3,h3}; \
    } \
    const f2 qs = (q0+q1)+(q2+q3); \
    const float aA = qs.x;                  /* lanes<32: i, lanes>=32: f */ \
    const float aB = qs.y;                  /* lanes<32: g, lanes>=32: o */ \
    const float fga = __shfl_xor(aA, 32);   /* lanes<32 receive f */ \
    const float oga = __shfl_xor(aB, 32);   /* lanes<32 receive o */ \
    const float cc = sigm(fga)*cst + sigm(aA)*tanh_(aB);  /* valid lanes<32 */ \
    cst = cc; \
    h = sigm(oga)*tanh_(cc);                               /* valid lanes<32 */ \
    if (l < 32) hring[((sidx) & 31)*36 + l] = h; \
  }

  for (int t = 0; t < S_; t += 4){
    float n0A=0.f, n0B=0.f, n1A=0.f, n1B=0.f, n2A=0.f, n2B=0.f, n3A=0.f, n3B=0.f;
    if (t + 4 < S_){                     // issue prefetch for steps t+4..t+7 FIRST
      const float* q = p0 + (ptrdiff_t)(t+4)*stp;
      n0A = q[0*stp + l]; n0B = q[0*stp + 64 + l];
      n1A = q[1*stp + l]; n1B = q[1*stp + 64 + l];
      n2A = q[2*stp + l]; n2B = q[2*stp + 64 + l];
      n3A = q[3*stp + l]; n3B = q[3*stp + 64 + l];
    }
    WSTEP(a0A, a0B, t+0)
    WSTEP(a1A, a1B, t+1)
    WSTEP(a2A, a2B, t+2)
    WSTEP(a3A, a3B, t+3)
    a0A=n0A; a0B=n0B; a1A=n1A; a1B=n1B;
    a2A=n2A; a2B=n2B; a3A=n3A; a3B=n3B;

    if ((t & 31) == 28){                 // flush steps s0..s0+31 coalesced
      const int s0 = t & ~31;
      const int srow = l >> 1, half = l & 1;
      const int s = s0 + srow;
      const int ss = d ? (S_ - 1 - s) : s;
      const float4* src = (const float4*)&hring[srow*36 + half*16];
      float4* dst = (float4*)(LO + ((size_t)n*S_ + ss)*64 + d*32 + half*16);
      dst[0] = src[0]; dst[1] = src[1]; dst[2] = src[2]; dst[3] = src[3];
    }
  }
#undef WSTEP
}

// ---------------- output head: sigmoid(lstm_out @ out_W^T + b) -> f32 ----------------
__global__ void k_out(const float* ws, const float* out_b, float* out){
  const int row = blockIdx.x*blockDim.x + threadIdx.x;
  const float4* lo = (const float4*)(ws + OFF_LO + (size_t)row*64);
  const float* OW = ws + OFF_OW;
  float a0 = out_b[0], a1 = out_b[1];
  #pragma unroll
  for (int q = 0; q < 16; ++q){
    const float4 v = lo[q];
    a0 += OW[q*4+0]*v.x + OW[q*4+1]*v.y + OW[q*4+2]*v.z + OW[q*4+3]*v.w;
    a1 += OW[64+q*4+0]*v.x + OW[64+q*4+1]*v.y + OW[64+q*4+2]*v.z + OW[64+q*4+3]*v.w;
  }
  out[row*2+0] = sigm(a0);
  out[row*2+1] = sigm(a1);
}

extern "C" void kernel_launch(void* const* d_in, const int* in_sizes, int n_in,
                              void* d_out, int out_size, void* d_ws, size_t ws_size,
                              hipStream_t stream){
  (void)in_sizes; (void)n_in; (void)out_size; (void)ws_size;
  const int*   word_ids   = (const int*)  d_in[0];
  const int*   char_ids   = (const int*)  d_in[1];
  const float* word_table = (const float*)d_in[2];
  const float* char_table = (const float*)d_in[3];
  const float* c_Wih_f    = (const float*)d_in[4];
  const float* c_Whh_f    = (const float*)d_in[5];
  const float* c_b_f      = (const float*)d_in[6];
  const float* c_Wih_b    = (const float*)d_in[7];
  const float* c_Whh_b    = (const float*)d_in[8];
  const float* c_b_b      = (const float*)d_in[9];
  const float* gen_W      = (const float*)d_in[10];
  const float* gen_b      = (const float*)d_in[11];
  const float* w_Wih_f    = (const float*)d_in[12];
  const float* w_Whh_f    = (const float*)d_in[13];
  const float* w_b_f      = (const float*)d_in[14];
  const float* w_Wih_b    = (const float*)d_in[15];
  const float* w_Whh_b    = (const float*)d_in[16];
  const float* w_b_b      = (const float*)d_in[17];
  const float* out_W      = (const float*)d_in[18];
  const float* out_b      = (const float*)d_in[19];
  float* ws  = (float*)d_ws;
  float* out = (float*)d_out;

  hipLaunchKernelGGL(k_prep,  dim3(64),   dim3(256), 0, stream,
                     gen_W, w_Wih_f, w_Wih_b, w_Whh_f, w_Whh_b, out_W, ws);
  hipLaunchKernelGGL(k_char,  dim3(1024), dim3(256), 0, stream,
                     char_ids, char_table, c_Wih_f, c_Whh_f, c_b_f,
                     c_Wih_b, c_Whh_b, c_b_b, ws);
  hipLaunchKernelGGL(k_genp,  dim3(512),  dim3(128), 0, stream,
                     word_ids, word_table, gen_b, w_b_f, w_b_b, ws);
  hipLaunchKernelGGL(k_wlstm, dim3(64),   dim3(64),  0, stream,
                     ws + OFF_WHHT, ws + OFF_PRE, ws + OFF_LO);
  hipLaunchKernelGGL(k_out,   dim3(64),   dim3(128), 0, stream, ws, out_b, out);
}

// Round 19
// 185.927 us; speedup vs baseline: 1.4971x; 1.0062x over previous
//
#include <hip/hip_runtime.h>
#include <hip/hip_bf16.h>

#define B_    32
#define S_    256
#define BS_   8192      // B_*S_
#define Wc_   16        // chars per word
#define CDIM_ 16
#define CH_   16
#define WDIM_ 300
#define KX_   332       // WDIM_+2*CH_
#define XC_   336       // padded X row (84 float4)
#define GEN_  100
#define WVP_  104       // padded word_vecs row
#define WH_   32
#define NG_   128       // 4*WH_

constexpr size_t OFF_WV   = 0;                                   // [8192][104] f32 (unused after fusion)
constexpr size_t OFF_PRE  = OFF_WV   + (size_t)BS_*WVP_;         // [2][256][32][128]
constexpr size_t OFF_LO   = OFF_PRE  + (size_t)2*S_*B_*NG_;      // [8192][64]
constexpr size_t OFF_CHB  = OFF_LO   + (size_t)BS_*64;           // [8192][32] char h
constexpr size_t OFF_GWT  = OFF_CHB  + (size_t)BS_*32;           // [332][128]
constexpr size_t OFF_WIHT = OFF_GWT  + (size_t)KX_*128;          // [2][100][128]
constexpr size_t OFF_WHHT = OFF_WIHT + (size_t)2*GEN_*NG_;       // [2][32][128]
constexpr size_t OFF_OW   = OFF_WHHT + (size_t)2*WH_*NG_;        // [2][64]

typedef __attribute__((ext_vector_type(2))) float f2;
typedef __attribute__((ext_vector_type(2))) unsigned u2;

// native-exp2 activations: v_exp_f32 + v_rcp_f32, ~3 insts vs ~11 for __ocml_expf
__device__ __forceinline__ float sigm(float x){
  return __builtin_amdgcn_rcpf(1.f + __builtin_amdgcn_exp2f(-1.44269504089f*x));
}
__device__ __forceinline__ float tanh_(float x){
  return 1.f - 2.f*__builtin_amdgcn_rcpf(1.f + __builtin_amdgcn_exp2f(2.88539008178f*x));
}
__device__ __forceinline__ float rdlane(float v, int lane){
  return __uint_as_float(__builtin_amdgcn_readlane(__float_as_uint(v), lane));
}
// 32-lane half exchange. Builtin permlane32_swap (VALU ~4cy) returns the
// (vdst_new, src_new) PAIR explicitly — allocation-safe, unlike the r18 asm
// identity trick (whose equal-valued "+v" operands could share a physical
// register and degenerate). With both inputs = v: r.x=[v.lo,v.lo],
// r.y=[v.hi,v.hi] -> partner = lo32 ? r.y : r.x.
#if defined(__has_builtin) && __has_builtin(__builtin_amdgcn_permlane32_swap)
__device__ __forceinline__ float xswap32(float v, bool lo32){
  u2 r = __builtin_amdgcn_permlane32_swap(__float_as_uint(v), __float_as_uint(v), false, false);
  return __uint_as_float(lo32 ? r.y : r.x);
}
#else
__device__ __forceinline__ float xswap32(float v, bool lo32){
  (void)lo32;
  return __shfl_xor(v, 32);
}
#endif

// ---------------- prep: transpose small weights ----------------
__global__ void k_prep(const float* gen_W, const float* wih_f, const float* wih_b,
                       const float* whh_f, const float* whh_b, const float* out_W,
                       float* ws){
  int idx = blockIdx.x*blockDim.x + threadIdx.x;
  int stride = gridDim.x*blockDim.x;
  for (int i = idx; i < GEN_*KX_; i += stride){       // gen_W [100][332] -> [k][j] stride 128
    int j = i / KX_, k = i - j*KX_;
    ws[OFF_GWT + (size_t)k*128 + j] = gen_W[i];
  }
  for (int i = idx; i < NG_*GEN_; i += stride){       // w_Wih [128][100] -> [k][g]
    int g = i / GEN_, k = i - g*GEN_;
    ws[OFF_WIHT + 0*GEN_*NG_ + (size_t)k*NG_ + g] = wih_f[i];
    ws[OFF_WIHT + 1*GEN_*NG_ + (size_t)k*NG_ + g] = wih_b[i];
  }
  for (int i = idx; i < NG_*WH_; i += stride){        // w_Whh [128][32] -> [k][g]
    int g = i / WH_, k = i - g*WH_;
    ws[OFF_WHHT + 0*WH_*NG_ + (size_t)k*NG_ + g] = whh_f[i];
    ws[OFF_WHHT + 1*WH_*NG_ + (size_t)k*NG_ + g] = whh_b[i];
  }
  for (int i = idx; i < 2*64; i += stride) ws[OFF_OW + i] = out_W[i];
}

// ---------------- char BiLSTM: lane = (seq, unit); 16 lanes/seq ----------------
__global__ void __launch_bounds__(256, 2) k_char(const int* char_ids, const float* char_table,
                       const float* Wih_f, const float* Whh_f, const float* b_f,
                       const float* Wih_b, const float* Whh_b, const float* b_b,
                       float* ws){
  __shared__ float xr[16*324];        // [s][t][k] row stride 20, s stride 324
  __shared__ float occ_pad[4864];     // 19KB: VGPR-budget lever
  const int dir = blockIdx.x & 1;
  const int sg  = blockIdx.x >> 1;
  const int tid = threadIdx.x;
  const float* WI = dir ? Wih_b : Wih_f;
  const float* WH = dir ? Whh_b : Whh_f;
  const float* BB = dir ? b_b  : b_f;
  const int ls = tid >> 4, u = tid & 15;
  const int seq0 = sg * 16;
  {
    const int id = char_ids[(seq0 + ls)*Wc_ + u];
    const float4* sr = (const float4*)(char_table + (size_t)id*CDIM_);
    float4 v0 = sr[0], v1 = sr[1], v2 = sr[2], v3 = sr[3];
    float* xw = &xr[ls*324 + u*20];
    *(float4*)(xw+0)  = v0; *(float4*)(xw+4)  = v1;
    *(float4*)(xw+8)  = v2; *(float4*)(xw+12) = v3;
    if (__builtin_expect(id == 0x7fffffff, 0)) occ_pad[tid] = v0.x;  // unprovable-dead
  }
  float wi[4][16];
  #pragma unroll
  for (int g = 0; g < 4; ++g){
    const float4* wr = (const float4*)(WI + (size_t)(g*16+u)*CDIM_);
    float4 a = wr[0], b = wr[1], c = wr[2], d = wr[3];
    wi[g][0]=a.x; wi[g][1]=a.y; wi[g][2]=a.z; wi[g][3]=a.w;
    wi[g][4]=b.x; wi[g][5]=b.y; wi[g][6]=b.z; wi[g][7]=b.w;
    wi[g][8]=c.x; wi[g][9]=c.y; wi[g][10]=c.z; wi[g][11]=c.w;
    wi[g][12]=d.x; wi[g][13]=d.y; wi[g][14]=d.z; wi[g][15]=d.w;
  }
  float bias[4];
  #pragma unroll
  for (int g = 0; g < 4; ++g) bias[g] = BB[g*16+u];
  __syncthreads();
  float xp[16][4];
  const float* xb = &xr[ls*324];
  #pragma unroll
  for (int p = 0; p < 16; ++p){
    const int tm = dir ? (15-p) : p;
    const float4 x0 = *(const float4*)(xb + tm*20 + 0);
    const float4 x1 = *(const float4*)(xb + tm*20 + 4);
    const float4 x2 = *(const float4*)(xb + tm*20 + 8);
    const float4 x3 = *(const float4*)(xb + tm*20 + 12);
    float xk[16] = {x0.x,x0.y,x0.z,x0.w, x1.x,x1.y,x1.z,x1.w,
                    x2.x,x2.y,x2.z,x2.w, x3.x,x3.y,x3.z,x3.w};
    #pragma unroll
    for (int g = 0; g < 4; ++g){
      float a0 = bias[g], a1 = 0.f;
      #pragma unroll
      for (int k = 0; k < 16; k += 2){ a0 += wi[g][k]*xk[k]; a1 += wi[g][k+1]*xk[k+1]; }
      xp[p][g] = a0 + a1;
    }
  }
  float wh[4][16];
  #pragma unroll
  for (int g = 0; g < 4; ++g){
    const float4* wr = (const float4*)(WH + (size_t)(g*16+u)*CH_);
    float4 a = wr[0], b = wr[1], c = wr[2], d = wr[3];
    wh[g][0]=a.x; wh[g][1]=a.y; wh[g][2]=a.z; wh[g][3]=a.w;
    wh[g][4]=b.x; wh[g][5]=b.y; wh[g][6]=b.z; wh[g][7]=b.w;
    wh[g][8]=c.x; wh[g][9]=c.y; wh[g][10]=c.z; wh[g][11]=c.w;
    wh[g][12]=d.x; wh[g][13]=d.y; wh[g][14]=d.z; wh[g][15]=d.w;
  }
  const int lbase = (tid & 63) & 48;
  float h = 0.f, c = 0.f;
  #pragma unroll
  for (int p = 0; p < 16; ++p){
    float ai = xp[p][0], af = xp[p][1], ag = xp[p][2], ao = xp[p][3];
    #pragma unroll
    for (int k = 0; k < 16; ++k){
      const float hk = __shfl(h, lbase + k, 64);
      ai += wh[0][k]*hk; af += wh[1][k]*hk;
      ag += wh[2][k]*hk; ao += wh[3][k]*hk;
    }
    c = sigm(af)*c + sigm(ai)*tanh_(ag);
    h = sigm(ao)*tanh_(c);
  }
  ws[OFF_CHB + (size_t)(seq0 + ls)*32 + dir*16 + u] = h;
}

// ---------------- fused gen + word-LSTM input projection ----------------
__global__ void k_genp(const int* word_ids, const float* word_table, const float* gen_b,
                       const float* wb_f, const float* wb_b, float* ws){
  __shared__ __align__(16) float xt[16*XC_];    // 21.5 KB
  __shared__ __align__(16) float wvs[16*WVP_];  // 6.5 KB
  __shared__ int wids[16];
  const int r0 = blockIdx.x*16;
  if (threadIdx.x < 16) wids[threadIdx.x] = word_ids[r0 + threadIdx.x];
  __syncthreads();
  float4* xt4 = (float4*)xt;
  for (int i = threadIdx.x; i < 16*75; i += 128){          // word part: 75 float4/row
    const int r = i/75, q = i - r*75;
    xt4[r*84 + q] = ((const float4*)(word_table + (size_t)wids[r]*WDIM_))[q];
  }
  for (int i = threadIdx.x; i < 16*8; i += 128){           // char part: 8 float4/row
    const int r = i >> 3, q = i & 7;
    xt4[r*84 + 75 + q] = ((const float4*)(ws + OFF_CHB + (size_t)(r0+r)*32))[q];
  }
  __syncthreads();
  const int j = threadIdx.x;                   // j<100 valid
  const float bj = (j < GEN_) ? gen_b[j] : 0.f;
  float acc[16];
  #pragma unroll
  for (int r = 0; r < 16; ++r) acc[r] = bj;
  const float* WT = ws + OFF_GWT;
  for (int k4 = 0; k4 < KX_/4; ++k4){
    const int k = k4*4;
    const float w0 = WT[(size_t)(k+0)*128 + j];
    const float w1 = WT[(size_t)(k+1)*128 + j];
    const float w2 = WT[(size_t)(k+2)*128 + j];
    const float w3 = WT[(size_t)(k+3)*128 + j];
    #pragma unroll
    for (int r = 0; r < 16; ++r){
      const float4 xv = xt4[r*84 + k4];
      acc[r] += w0*xv.x + w1*xv.y + w2*xv.z + w3*xv.w;
    }
  }
  if (j < GEN_){
    #pragma unroll
    for (int r = 0; r < 16; ++r){
      const float a = acc[r];
      wvs[r*WVP_ + j] = 0.5f*a*(1.f + erff(a*0.70710678118f));
    }
  }
  __syncthreads();
  // phase 2: pre-activation projection for both directions
  const int g = threadIdx.x;                   // all 128 valid
  #pragma unroll
  for (int d = 0; d < 2; ++d){
    const float* W2 = ws + OFF_WIHT + (size_t)d*GEN_*NG_;
    const float wb = (d ? wb_b : wb_f)[g];
    float ac2[16];
    #pragma unroll
    for (int r = 0; r < 16; ++r) ac2[r] = wb;
    for (int k4 = 0; k4 < GEN_/4; ++k4){
      const int k = k4*4;
      const float w0 = W2[(size_t)(k+0)*NG_ + g];
      const float w1 = W2[(size_t)(k+1)*NG_ + g];
      const float w2 = W2[(size_t)(k+2)*NG_ + g];
      const float w3 = W2[(size_t)(k+3)*NG_ + g];
      #pragma unroll
      for (int r = 0; r < 16; ++r){
        const float4 xv = *(const float4*)&wvs[r*WVP_ + k];
        ac2[r] += w0*xv.x + w1*xv.y + w2*xv.z + w3*xv.w;
      }
    }
    float* pre = ws + OFF_PRE + (size_t)d*S_*B_*NG_;
    #pragma unroll
    for (int r = 0; r < 16; ++r){
      const int row = r0 + r, bb = row >> 8, ss = row & 255;
      pre[((size_t)ss*B_ + bb)*NG_ + g] = ac2[r];
    }
  }
}

// ---------------- word BiLSTM scan: 1 wave per (dir, batch row), packed FMAs ----------------
// r19 = r16 structure with ONLY the half-exchange changed: __shfl_xor
// (ds_bpermute, ~100cy LDS-pipe on the serial chain) -> permlane32_swap
// builtin (VALU ~4cy, allocation-safe pair return).
#define BN_ ((size_t)B_*NG_)
__global__ void __launch_bounds__(64) k_wlstm(const float* __restrict__ WHT,
                                              const float* __restrict__ PRE,
                                              float* __restrict__ LO){
  __shared__ __align__(16) float hring[5632];   // [32][36] used; size = VGPR-budget lever (r12)
  const int pair = blockIdx.x;          // 0..63
  const int d = pair >> 5;
  const int n = pair & 31;
  const int l = threadIdx.x;
  const bool lo32 = (l < 32);
  const float* WT = WHT + (size_t)d*WH_*NG_;
  f2 w2[32];                            // (wA[k], wB[k]) — gates l and 64+l
  #pragma unroll
  for (int k = 0; k < 32; ++k){
    w2[k] = (f2){ WT[(size_t)k*NG_ + l], WT[(size_t)k*NG_ + 64 + l] };
  }
  const float* pre = PRE + (size_t)d*S_*BN_ + (size_t)n*NG_;
  const float* p0 = pre + (size_t)(d ? (S_-1) : 0)*BN_;
  const ptrdiff_t stp = (d ? -1 : 1) * (ptrdiff_t)BN_;
  float cst = 0.f, h = 0.f;

  // prefetch steps 0..3
  float a0A = p0[0*stp + l], a0B = p0[0*stp + 64 + l];
  float a1A = p0[1*stp + l], a1B = p0[1*stp + 64 + l];
  float a2A = p0[2*stp + l], a2B = p0[2*stp + 64 + l];
  float a3A = p0[3*stp + l], a3B = p0[3*stp + 64 + l];

#define WSTEP(pAv, pBv, sidx) { \
    f2 q0 = (f2){(pAv),(pBv)}, q1 = (f2){0.f,0.f}, q2 = (f2){0.f,0.f}, q3 = (f2){0.f,0.f}; \
    _Pragma("unroll") \
    for (int k = 0; k < 32; k += 4){ \
      const float h0 = rdlane(h, k+0); \
      const float h1 = rdlane(h, k+1); \
      const float h2 = rdlane(h, k+2); \
      const float h3 = rdlane(h, k+3); \
      q0 += w2[k+0] * (f2){h0,h0}; \
      q1 += w2[k+1] * (f2){h1,h1}; \
      q2 += w2[k+2] * (f2){h2,h2}; \
      q3 += w2[k+3] * (f2){h3,h3}; \
    } \
    const f2 qs = (q0+q1)+(q2+q3); \
    const float aA = qs.x;                  /* lanes<32: i, lanes>=32: f */ \
    const float aB = qs.y;                  /* lanes<32: g, lanes>=32: o */ \
    const float fga = xswap32(aA, lo32);    /* lanes<32 receive f */ \
    const float oga = xswap32(aB, lo32);    /* lanes<32 receive o */ \
    const float cc = sigm(fga)*cst + sigm(aA)*tanh_(aB);  /* valid lanes<32 */ \
    cst = cc; \
    h = sigm(oga)*tanh_(cc);                               /* valid lanes<32 */ \
    if (lo32) hring[((sidx) & 31)*36 + l] = h; \
  }

  for (int t = 0; t < S_; t += 4){
    float n0A=0.f, n0B=0.f, n1A=0.f, n1B=0.f, n2A=0.f, n2B=0.f, n3A=0.f, n3B=0.f;
    if (t + 4 < S_){                     // issue prefetch for steps t+4..t+7 FIRST
      const float* q = p0 + (ptrdiff_t)(t+4)*stp;
      n0A = q[0*stp + l]; n0B = q[0*stp + 64 + l];
      n1A = q[1*stp + l]; n1B = q[1*stp + 64 + l];
      n2A = q[2*stp + l]; n2B = q[2*stp + 64 + l];
      n3A = q[3*stp + l]; n3B = q[3*stp + 64 + l];
    }
    WSTEP(a0A, a0B, t+0)
    WSTEP(a1A, a1B, t+1)
    WSTEP(a2A, a2B, t+2)
    WSTEP(a3A, a3B, t+3)
    a0A=n0A; a0B=n0B; a1A=n1A; a1B=n1B;
    a2A=n2A; a2B=n2B; a3A=n3A; a3B=n3B;

    if ((t & 31) == 28){                 // flush steps s0..s0+31 coalesced
      const int s0 = t & ~31;
      const int srow = l >> 1, half = l & 1;
      const int s = s0 + srow;
      const int ss = d ? (S_ - 1 - s) : s;
      const float4* src = (const float4*)&hring[srow*36 + half*16];
      float4* dst = (float4*)(LO + ((size_t)n*S_ + ss)*64 + d*32 + half*16);
      dst[0] = src[0]; dst[1] = src[1]; dst[2] = src[2]; dst[3] = src[3];
    }
  }
#undef WSTEP
}

// ---------------- output head: sigmoid(lstm_out @ out_W^T + b) -> f32 ----------------
__global__ void k_out(const float* ws, const float* out_b, float* out){
  const int row = blockIdx.x*blockDim.x + threadIdx.x;
  const float4* lo = (const float4*)(ws + OFF_LO + (size_t)row*64);
  const float* OW = ws + OFF_OW;
  float a0 = out_b[0], a1 = out_b[1];
  #pragma unroll
  for (int q = 0; q < 16; ++q){
    const float4 v = lo[q];
    a0 += OW[q*4+0]*v.x + OW[q*4+1]*v.y + OW[q*4+2]*v.z + OW[q*4+3]*v.w;
    a1 += OW[64+q*4+0]*v.x + OW[64+q*4+1]*v.y + OW[64+q*4+2]*v.z + OW[64+q*4+3]*v.w;
  }
  out[row*2+0] = sigm(a0);
  out[row*2+1] = sigm(a1);
}

extern "C" void kernel_launch(void* const* d_in, const int* in_sizes, int n_in,
                              void* d_out, int out_size, void* d_ws, size_t ws_size,
                              hipStream_t stream){
  (void)in_sizes; (void)n_in; (void)out_size; (void)ws_size;
  const int*   word_ids   = (const int*)  d_in[0];
  const int*   char_ids   = (const int*)  d_in[1];
  const float* word_table = (const float*)d_in[2];
  const float* char_table = (const float*)d_in[3];
  const float* c_Wih_f    = (const float*)d_in[4];
  const float* c_Whh_f    = (const float*)d_in[5];
  const float* c_b_f      = (const float*)d_in[6];
  const float* c_Wih_b    = (const float*)d_in[7];
  const float* c_Whh_b    = (const float*)d_in[8];
  const float* c_b_b      = (const float*)d_in[9];
  const float* gen_W      = (const float*)d_in[10];
  const float* gen_b      = (const float*)d_in[11];
  const float* w_Wih_f    = (const float*)d_in[12];
  const float* w_Whh_f    = (const float*)d_in[13];
  const float* w_b_f      = (const float*)d_in[14];
  const float* w_Wih_b    = (const float*)d_in[15];
  const float* w_Whh_b    = (const float*)d_in[16];
  const float* w_b_b      = (const float*)d_in[17];
  const float* out_W      = (const float*)d_in[18];
  const float* out_b      = (const float*)d_in[19];
  float* ws  = (float*)d_ws;
  float* out = (float*)d_out;

  hipLaunchKernelGGL(k_prep,  dim3(64),   dim3(256), 0, stream,
                     gen_W, w_Wih_f, w_Wih_b, w_Whh_f, w_Whh_b, out_W, ws);
  hipLaunchKernelGGL(k_char,  dim3(1024), dim3(256), 0, stream,
                     char_ids, char_table, c_Wih_f, c_Whh_f, c_b_f,
                     c_Wih_b, c_Whh_b, c_b_b, ws);
  hipLaunchKernelGGL(k_genp,  dim3(512),  dim3(128), 0, stream,
                     word_ids, word_table, gen_b, w_b_f, w_b_b, ws);
  hipLaunchKernelGGL(k_wlstm, dim3(64),   dim3(64),  0, stream,
                     ws + OFF_WHHT, ws + OFF_PRE, ws + OFF_LO);
  hipLaunchKernelGGL(k_out,   dim3(64),   dim3(128), 0, stream, ws, out_b, out);
}